// Round 6
// baseline (838.257 us; speedup 1.0000x reference)
//
#include <hip/hip_runtime.h>
#include <hip/hip_bf16.h>
#include <math.h>

#define BQ 2
#define NV 6
#define CIN 64
#define HF 32
#define WF 56
#define ND 32
#define BEVC 128
#define BEVH 128
#define BEVW 128
#define NPIX (HF*WF)     // 1792
#define BV (BQ*NV)       // 12
#define NCOL (BV*WF)     // 672
#define NITEM (NCOL*ND)  // 21504
#define NCELL (BQ*BEVH*BEVW) // 32768
#define EXT 20.0f
#define BN_S 0.99999500003749937f

typedef short bf16x8 __attribute__((ext_vector_type(8)));
typedef float f32x4 __attribute__((ext_vector_type(4)));

__device__ __forceinline__ float gelu(float x) {
    return 0.5f * x * (1.0f + erff(x * 0.70710678118654752f));
}

__device__ __forceinline__ unsigned short f2bf(float x) {
    union { float f; unsigned u; } v; v.f = x;
    unsigned r = v.u + 0x7FFFu + ((v.u >> 16) & 1u);
    return (unsigned short)(r >> 16);
}

// ---------------- Kernel 1: 3x3 conv 64->64, *BN_S, gelu. NCHW in/out ----------------
#define COG 16
__global__ void k_conv1(const float* __restrict__ fm, const float* __restrict__ w,
                        const float* __restrict__ bias, float* __restrict__ out) {
    int g   = blockIdx.x * 256 + threadIdx.x;
    int co0 = blockIdx.y * COG;
    int bv  = g / NPIX, pix = g % NPIX;
    int py  = pix / WF, px = pix % WF;
    const float* in0 = fm + (size_t)bv * CIN * NPIX + py * WF + px;

    bool ym[3], xm[3];
    #pragma unroll
    for (int d = 0; d < 3; d++) {
        ym[d] = (unsigned)(py + d - 1) < (unsigned)HF;
        xm[d] = (unsigned)(px + d - 1) < (unsigned)WF;
    }

    float acc[COG];
    #pragma unroll
    for (int c = 0; c < COG; c++) acc[c] = bias[co0 + c];

    for (int ci = 0; ci < CIN; ci++) {
        const float* ip = in0 + ci * NPIX;
        float v[9];
        #pragma unroll
        for (int dy = 0; dy < 3; dy++)
            #pragma unroll
            for (int dx = 0; dx < 3; dx++)
                v[dy * 3 + dx] = (ym[dy] && xm[dx]) ? ip[(dy - 1) * WF + (dx - 1)] : 0.0f;
        const float* wp = w + ((size_t)co0 * CIN + ci) * 9;  // wave-uniform -> s_load
        #pragma unroll
        for (int c = 0; c < COG; c++)
            #pragma unroll
            for (int k = 0; k < 9; k++)
                acc[c] += wp[(size_t)c * CIN * 9 + k] * v[k];
    }

    float* op = out + (size_t)bv * CIN * NPIX + (size_t)co0 * NPIX + pix;
    #pragma unroll
    for (int c = 0; c < COG; c++) op[(size_t)c * NPIX] = gelu(acc[c] * BN_S);
}

// ---------------- Kernel 2: 1x1 conv 64->32 + softmax over 32. out [p][d] ----------------
__global__ void k_depth(const float* __restrict__ h, const float* __restrict__ w,
                        const float* __restrict__ bias, float* __restrict__ dp) {
    __shared__ float wl[ND * CIN];
    __shared__ float bl[ND];
    for (int i = threadIdx.x; i < ND * CIN; i += 256) wl[i] = w[i];
    if (threadIdx.x < ND) bl[threadIdx.x] = bias[threadIdx.x];
    __syncthreads();
    int g = blockIdx.x * 256 + threadIdx.x;
    if (g >= BV * NPIX) return;
    int bv = g / NPIX, pix = g % NPIX;
    float hv[CIN];
    const float* hp = h + (size_t)bv * CIN * NPIX + pix;
    #pragma unroll
    for (int ci = 0; ci < CIN; ci++) hv[ci] = hp[ci * NPIX];
    float o[ND];
    float mx = -1e30f;
    #pragma unroll
    for (int d = 0; d < ND; d++) {
        float acc = bl[d];
        #pragma unroll
        for (int ci = 0; ci < CIN; ci++) acc += wl[d * CIN + ci] * hv[ci];
        o[d] = acc;
        mx = fmaxf(mx, acc);
    }
    float s = 0.f;
    #pragma unroll
    for (int d = 0; d < ND; d++) { o[d] = expf(o[d] - mx); s += o[d]; }
    float inv = 1.0f / s;
    float* op = dp + (size_t)g * ND;
    #pragma unroll
    for (int d = 0; d < ND; d++) op[d] = o[d] * inv;
}

// ---------------- Kernel 3: 1x1 conv 64->128, *BN_S, gelu. out [p][co] ----------------
// block 256 = 128 co x 2 pixel-halves; 16 pixels per block. Weights in registers,
// input tile in LDS (conflict-free), broadcast reads, coalesced stores.
#define FPPIX 16
__global__ void k_fp(const float* __restrict__ fm, const float* __restrict__ w,
                     const float* __restrict__ bias, float* __restrict__ fp) {
    __shared__ float il[CIN * FPPIX];
    int co   = threadIdx.x & 127;
    int half = threadIdx.x >> 7;
    int p0 = blockIdx.x * FPPIX;          // NPIX % 16 == 0 -> no bv crossing
    int bv = p0 / NPIX, pix = p0 % NPIX;
    const float* ip = fm + (size_t)bv * CIN * NPIX + pix;

    for (int i = threadIdx.x; i < CIN * FPPIX; i += 256) {
        int ci = i >> 4, pl = i & 15;
        il[i] = ip[ci * NPIX + pl];
    }

    float wreg[CIN];
    const float* wp = w + (size_t)co * CIN;
    #pragma unroll
    for (int ci = 0; ci < CIN; ci++) wreg[ci] = wp[ci];
    __syncthreads();

    float acc[8];
    float bi = bias[co];
    #pragma unroll
    for (int p = 0; p < 8; p++) acc[p] = bi;
    #pragma unroll
    for (int ci = 0; ci < CIN; ci++) {
        float wv = wreg[ci];
        #pragma unroll
        for (int p = 0; p < 8; p++)
            acc[p] += wv * il[ci * 16 + half * 8 + p];
    }
    #pragma unroll
    for (int p = 0; p < 8; p++)
        fp[(size_t)(p0 + half * 8 + p) * BEVC + co] = gelu(acc[p] * BN_S);
}

// ---------------- geometry helper: BEV cell for (bv,px,py,di). Reference op order. ----------------
struct Geo {
    float i00,i01,i02,i10,i11,i12,i20,i21,i22;
    float R00,R01,R02,t0,R10,R11,R12,t1;
};
__device__ __forceinline__ Geo load_geo(const float* Km, const float* Tm, int bv) {
    Geo G;
    const float* Kp = Km + bv * 9;
    float a = Kp[0], bb = Kp[1], cc = Kp[2];
    float d = Kp[3], e  = Kp[4], f  = Kp[5];
    float g = Kp[6], hh = Kp[7], ii = Kp[8];
    float A  = e * ii - f * hh;
    float Bm = -(d * ii - f * g);
    float Cm = d * hh - e * g;
    float det = a * A + bb * Bm + cc * Cm;
    float invd = 1.0f / det;
    G.i00 = A * invd;  G.i01 = -(bb * ii - cc * hh) * invd; G.i02 = (bb * f - cc * e) * invd;
    G.i10 = Bm * invd; G.i11 = (a * ii - cc * g) * invd;    G.i12 = -(a * f - cc * d) * invd;
    G.i20 = Cm * invd; G.i21 = -(a * hh - bb * g) * invd;   G.i22 = (a * e - bb * d) * invd;
    const float* Tp = Tm + bv * 16;
    G.R00 = Tp[0]; G.R01 = Tp[1]; G.R02 = Tp[2]; G.t0 = Tp[3];
    G.R10 = Tp[4]; G.R11 = Tp[5]; G.R12 = Tp[6]; G.t1 = Tp[7];
    return G;
}
__device__ __forceinline__ int geo_cell(const Geo& G, int px, int py, float dep) {
    float fx = (float)px, fy = (float)py;
    float r0 = G.i00 * fx + G.i01 * fy + G.i02;
    float r1 = G.i10 * fx + G.i11 * fy + G.i12;
    float r2 = G.i20 * fx + G.i21 * fy + G.i22;
    float xe = G.R00 * (r0 * dep) + G.R01 * (r1 * dep) + G.R02 * (r2 * dep) + G.t0;
    float ye = G.R10 * (r0 * dep) + G.R11 * (r1 * dep) + G.R12 * (r2 * dep) + G.t1;
    int col = (int)((xe + EXT) / (2.0f * EXT) * (float)(BEVW - 1));
    int row = (int)((ye + EXT) / (2.0f * EXT) * (float)(BEVH - 1));
    return (col >= 0 && col < BEVW && row >= 0 && row < BEVH) ? row * BEVW + col : -1;
}

// ---------------- Kernel 4a: per-column py-pre-reduction -> M rows + cell ids (no atomics) ----
__global__ void k_prered(const float* __restrict__ fp, const float* __restrict__ dp,
                         const float* __restrict__ Km, const float* __restrict__ Tm,
                         const float* __restrict__ trust, const float* __restrict__ depths,
                         float* __restrict__ M, int* __restrict__ cellidx) {
    __shared__ float fpl[HF * BEVC];   // [py][c], pre-scaled by trust
    __shared__ float dpl[HF * ND];     // [py][di]
    __shared__ int   celll[ND * HF];   // [di][py]
    __shared__ int   uni[ND];

    int col = blockIdx.x;
    int bv = col / WF, px = col % WF;
    int b  = bv / NV;
    float tw = trust[bv];

    for (int i = threadIdx.x; i < HF * (BEVC / 4); i += 256) {
        int py = i >> 5, c4 = i & 31;
        float4 v = ((const float4*)(fp + ((size_t)bv * NPIX + py * WF + px) * BEVC))[c4];
        v.x *= tw; v.y *= tw; v.z *= tw; v.w *= tw;
        ((float4*)fpl)[py * 32 + c4] = v;
    }
    for (int i = threadIdx.x; i < HF * (ND / 4); i += 256) {
        int py = i >> 3, d4 = i & 7;
        ((float4*)dpl)[py * 8 + d4] =
            ((const float4*)(dp + ((size_t)bv * NPIX + py * WF + px) * ND))[d4];
    }

    Geo G = load_geo(Km, Tm, bv);
    for (int q = threadIdx.x; q < ND * HF; q += 256) {
        int di = q >> 5, py = q & 31;
        celll[q] = geo_cell(G, px, py, depths[di]);
    }
    __syncthreads();

    if (threadIdx.x < ND) {
        int di = threadIdx.x;
        int c0 = celll[di * HF];
        bool u = true;
        for (int py = 1; py < HF; py++) u &= (celll[di * HF + py] == c0);
        uni[di] = u ? c0 : -2;
    }
    __syncthreads();

    int c = threadIdx.x & 127, dg = threadIdx.x >> 7;
    float acc[16];
    #pragma unroll
    for (int k = 0; k < 16; k++) acc[k] = 0.f;
    for (int py = 0; py < HF; py++) {
        float fv = fpl[py * BEVC + c];
        #pragma unroll
        for (int k = 0; k < 16; k++)
            acc[k] += fv * dpl[py * ND + dg * 16 + k];
    }
    #pragma unroll
    for (int k = 0; k < 16; k++)
        M[((size_t)col * ND + dg * 16 + k) * BEVC + c] = acc[k];

    if (threadIdx.x < ND) {
        int u = uni[threadIdx.x];
        cellidx[col * ND + threadIdx.x] = (u >= 0) ? (b * (BEVH * BEVW) + u) : u;
    }
}

// ---------------- Kernel 4b/c/d: counting sort by cell ----------------
__global__ void k_hist(const int* __restrict__ cellidx, int* __restrict__ count) {
    int i = blockIdx.x * 256 + threadIdx.x;
    if (i >= NITEM) return;
    int c = cellidx[i];
    if (c >= 0) atomicAdd(&count[c], 1);
}

__global__ void k_scan(const int* __restrict__ count, int* __restrict__ offs,
                       int* __restrict__ cursor) {
    __shared__ int part[1024];
    int t = threadIdx.x;
    int base = t * 32;
    int loc[32];
    int s = 0;
    #pragma unroll
    for (int i = 0; i < 32; i++) { loc[i] = s; s += count[base + i]; }
    part[t] = s;
    __syncthreads();
    for (int off = 1; off < 1024; off <<= 1) {
        int v = (t >= off) ? part[t - off] : 0;
        __syncthreads();
        part[t] += v;
        __syncthreads();
    }
    int pre = (t == 0) ? 0 : part[t - 1];
    #pragma unroll
    for (int i = 0; i < 32; i++) {
        offs[base + i] = pre + loc[i];
        cursor[base + i] = pre + loc[i];
    }
    if (t == 1023) offs[NCELL] = pre + s;
}

__global__ void k_fill(const int* __restrict__ cellidx, int* __restrict__ cursor,
                       int* __restrict__ itemlist) {
    int i = blockIdx.x * 256 + threadIdx.x;
    if (i >= NITEM) return;
    int c = cellidx[i];
    if (c >= 0) {
        int p = atomicAdd(&cursor[c], 1);
        itemlist[p] = i;
    }
}

// ---------------- Kernel 4e: gather. block = cell (128 thr = channels). bev written once. ----
__global__ void k_gather(const float* __restrict__ M, const int* __restrict__ offs,
                         const int* __restrict__ itemlist, float* __restrict__ bev) {
    int cell = blockIdx.x;
    int s = offs[cell], e = offs[cell + 1];
    int c = threadIdx.x;
    float acc = 0.f;
    for (int j = s; j < e; j++) {
        int it = itemlist[j];               // wave-uniform scalar load
        acc += M[(size_t)it * BEVC + c];
    }
    bev[(size_t)cell * BEVC + c] = acc;
}

// ---------------- Kernel 4f: generic fallback for non-uniform columns (normally no-op) ----
__global__ void k_fallback(const float* __restrict__ fp, const float* __restrict__ dp,
                           const float* __restrict__ Km, const float* __restrict__ Tm,
                           const float* __restrict__ trust, const float* __restrict__ depths,
                           const int* __restrict__ cellidx, float* __restrict__ bev) {
    int col = blockIdx.x;
    bool any = false;
    for (int di = 0; di < ND; di++) any |= (cellidx[col * ND + di] == -2);
    if (!any) return;

    int bv = col / WF, px = col % WF;
    int b  = bv / NV;
    float tw = trust[bv];
    Geo G = load_geo(Km, Tm, bv);
    int c = threadIdx.x;
    float* bevb = bev + (size_t)b * BEVH * BEVW * BEVC;
    for (int di = 0; di < ND; di++) {
        if (cellidx[col * ND + di] != -2) continue;
        float dep = depths[di];
        for (int py = 0; py < HF; py++) {
            int cell = geo_cell(G, px, py, dep);
            if (cell >= 0) {
                float v = fp[((size_t)bv * NPIX + py * WF + px) * BEVC + c] * tw *
                          dp[((size_t)bv * NPIX + py * WF + px) * ND + di];
                atomicAdd(&bevb[(size_t)cell * BEVC + c], v);
            }
        }
    }
}

// ---------------- weight prep: w[co][ci][3][3] fp32 -> fragment-linear bf16 ----------------
__global__ void k_wprep(const float* __restrict__ w, unsigned short* __restrict__ wf) {
    int i = blockIdx.x * 256 + threadIdx.x;
    if (i >= 9 * 4 * 8 * 64 * 8) return;
    int e     = i & 7;
    int lane  = (i >> 3) & 63;
    int ntile = (i >> 9) & 7;
    int kstep = (i >> 12) & 3;
    int kpos  = i >> 14;
    int co = ntile * 16 + (lane & 15);
    int ci = kstep * 32 + ((lane >> 4) << 3) + e;
    wf[i] = f2bf(w[((size_t)co * BEVC + ci) * 9 + kpos]);
}

// ---------------- Kernel 5/6: 3x3 conv 128->128 NHWC via MFMA bf16 ----------------
#define TX2 16
#define TY2 4
#define HALO_W 18
#define HALO_H 6
#define HP (HALO_W*HALO_H)   // 108

__device__ __forceinline__ int swz(int pix, int off) {
    return pix * 256 + (off ^ ((pix & 7) << 4));
}

template<int TI_BF, int TO_BF>
__global__ void k_bevconv(const void* __restrict__ in_, const unsigned short* __restrict__ wfrag,
                          const float* __restrict__ bias, void* __restrict__ out_) {
    __shared__ char ldsb[HP * 256];   // [pix(108)][ci(128) bf16], XOR-swizzled
    int x0 = blockIdx.x * TX2;
    int y0 = blockIdx.y * TY2;
    int b  = blockIdx.z;

    for (int t = threadIdx.x; t < HP * 16; t += 256) {
        int pix = t >> 4, oct = t & 15;
        int r = pix / HALO_W, c = pix % HALO_W;
        int gy = y0 + r - 1, gx = x0 + c - 1;
        int4 w4 = {0, 0, 0, 0};
        if ((unsigned)gy < (unsigned)BEVH && (unsigned)gx < (unsigned)BEVW) {
            size_t base = ((size_t)(b * BEVH + gy) * BEVW + gx) * BEVC + oct * 8;
            if (TI_BF) {
                w4 = *(const int4*)((const unsigned short*)in_ + base);
            } else {
                const float* p = (const float*)in_ + base;
                float4 f0 = ((const float4*)p)[0];
                float4 f1 = ((const float4*)p)[1];
                w4.x = f2bf(f0.x) | ((int)f2bf(f0.y) << 16);
                w4.y = f2bf(f0.z) | ((int)f2bf(f0.w) << 16);
                w4.z = f2bf(f1.x) | ((int)f2bf(f1.y) << 16);
                w4.w = f2bf(f1.z) | ((int)f2bf(f1.w) << 16);
            }
        }
        *(int4*)(ldsb + swz(pix, oct * 16)) = w4;
    }
    __syncthreads();

    int wave = threadIdx.x >> 6;
    int lane = threadIdx.x & 63;
    int xx   = lane & 15;
    int kgrp = lane >> 4;

    const bf16x8* wv = (const bf16x8*)wfrag;

    f32x4 acc[TY2][2];
    {
        float b0 = bias[wave * 32 + (lane & 15)];
        float b1 = bias[wave * 32 + 16 + (lane & 15)];
        #pragma unroll
        for (int m = 0; m < TY2; m++) {
            acc[m][0] = (f32x4){b0, b0, b0, b0};
            acc[m][1] = (f32x4){b1, b1, b1, b1};
        }
    }

    for (int kpos = 0; kpos < 9; kpos++) {
        int dy = kpos / 3, dx = kpos % 3;
        #pragma unroll
        for (int kstep = 0; kstep < 4; kstep++) {
            bf16x8 bf0 = wv[((kpos * 4 + kstep) * 8 + wave * 2 + 0) * 64 + lane];
            bf16x8 bf1 = wv[((kpos * 4 + kstep) * 8 + wave * 2 + 1) * 64 + lane];
            #pragma unroll
            for (int m = 0; m < TY2; m++) {
                bf16x8 a = *(const bf16x8*)(ldsb + swz((m + dy) * HALO_W + xx + dx,
                                                       kstep * 64 + kgrp * 16));
                acc[m][0] = __builtin_amdgcn_mfma_f32_16x16x32_bf16(a, bf0, acc[m][0], 0, 0, 0);
                acc[m][1] = __builtin_amdgcn_mfma_f32_16x16x32_bf16(a, bf1, acc[m][1], 0, 0, 0);
            }
        }
    }

    #pragma unroll
    for (int m = 0; m < TY2; m++) {
        int gy = y0 + m;
        #pragma unroll
        for (int n = 0; n < 2; n++) {
            int co = wave * 32 + n * 16 + (lane & 15);
            #pragma unroll
            for (int r = 0; r < 4; r++) {
                int gx = x0 + kgrp * 4 + r;
                float v = gelu(acc[m][n][r] * BN_S);
                size_t oi = ((size_t)(b * BEVH + gy) * BEVW + gx) * BEVC + co;
                if (TO_BF) ((unsigned short*)out_)[oi] = f2bf(v);
                else       ((float*)out_)[oi] = v;
            }
        }
    }
}

// ---------------- NHWC -> NCHW transpose for final output ----------------
__global__ void k_to_nchw(const float* __restrict__ in, float* __restrict__ out) {
    __shared__ float t[64][65];
    int b = blockIdx.z;
    int y = blockIdx.y;
    int xt = (blockIdx.x & 1) * 64;
    int ct = (blockIdx.x >> 1) * 64;
    int lc = threadIdx.x & 63;
    int lr = threadIdx.x >> 6;
    #pragma unroll
    for (int i = 0; i < 16; i++) {
        int xi = lr + i * 4;
        t[xi][lc] = in[(((size_t)b * BEVH + y) * BEVW + xt + xi) * BEVC + ct + lc];
    }
    __syncthreads();
    #pragma unroll
    for (int i = 0; i < 16; i++) {
        int ci = lr + i * 4;
        out[(((size_t)b * BEVC + ct + ci) * BEVH + y) * BEVW + xt + lc] = t[lc][ci];
    }
}

extern "C" void kernel_launch(void* const* d_in, const int* in_sizes, int n_in,
                              void* d_out, int out_size, void* d_ws, size_t ws_size,
                              hipStream_t stream) {
    const float* feat_maps = (const float*)d_in[0];
    const float* Km        = (const float*)d_in[1];
    const float* Tm        = (const float*)d_in[2];
    const float* trust     = (const float*)d_in[3];
    const float* depths    = (const float*)d_in[4];
    const float* dh_w1     = (const float*)d_in[5];
    const float* dh_b1     = (const float*)d_in[6];
    const float* dh_w2     = (const float*)d_in[7];
    const float* dh_b2     = (const float*)d_in[8];
    const float* fp_w      = (const float*)d_in[9];
    const float* fp_b      = (const float*)d_in[10];
    const float* br_w1     = (const float*)d_in[11];
    const float* br_b1     = (const float*)d_in[12];
    const float* br_w2     = (const float*)d_in[13];
    const float* br_b2     = (const float*)d_in[14];
    float* out = (float*)d_out;

    float* ws  = (float*)d_ws;
    float* h1  = ws;                                     // 12*64*1792 f
    float* dpb = h1 + (size_t)BV * CIN * NPIX;           // 12*1792*32 f
    float* fpb = dpb + (size_t)BV * NPIX * ND;           // 12*1792*128 f
    float* bev = fpb + (size_t)BV * NPIX * BEVC;         // 2*16384*128 f
    float* o2  = bev + (size_t)BQ * BEVH * BEVW * BEVC;  // 2*16384*128 f
    float* Mb  = o2 + (size_t)BQ * BEVH * BEVW * BEVC;   // 21504*128 f
    unsigned short* h2b = (unsigned short*)(Mb + (size_t)NITEM * BEVC); // bf16, NCELL*128
    unsigned short* wf1 = h2b + (size_t)BQ * BEVH * BEVW * BEVC;
    unsigned short* wf2 = wf1 + (size_t)9 * 4 * 8 * 64 * 8;
    int* cellidx  = (int*)(wf2 + (size_t)9 * 4 * 8 * 64 * 8); // NITEM
    int* count    = cellidx + NITEM;        // NCELL
    int* offs     = count + NCELL;          // NCELL+1
    int* cursor   = offs + NCELL + 1;       // NCELL
    int* itemlist = cursor + NCELL;         // NITEM

    // weight prep (fragment-linear bf16)
    k_wprep<<<dim3((9 * 4 * 8 * 64 * 8 + 255) / 256), dim3(256), 0, stream>>>(br_w1, wf1);
    k_wprep<<<dim3((9 * 4 * 8 * 64 * 8 + 255) / 256), dim3(256), 0, stream>>>(br_w2, wf2);

    // depth-head conv1 + gelu
    k_conv1<<<dim3(BV * NPIX / 256, CIN / COG), dim3(256), 0, stream>>>(feat_maps, dh_w1, dh_b1, h1);

    // depth probs
    k_depth<<<dim3(BV * NPIX / 256), dim3(256), 0, stream>>>(h1, dh_w2, dh_b2, dpb);

    // feature projection
    k_fp<<<dim3(BV * NPIX / FPPIX), dim3(256), 0, stream>>>(feat_maps, fp_w, fp_b, fpb);

    // --- scatter via sort+gather (no fp32 atomics) ---
    k_prered<<<dim3(NCOL), dim3(256), 0, stream>>>(fpb, dpb, Km, Tm, trust, depths, Mb, cellidx);
    hipMemsetAsync(count, 0, NCELL * sizeof(int), stream);
    k_hist<<<dim3((NITEM + 255) / 256), dim3(256), 0, stream>>>(cellidx, count);
    k_scan<<<dim3(1), dim3(1024), 0, stream>>>(count, offs, cursor);
    k_fill<<<dim3((NITEM + 255) / 256), dim3(256), 0, stream>>>(cellidx, cursor, itemlist);
    k_gather<<<dim3(NCELL), dim3(BEVC), 0, stream>>>(Mb, offs, itemlist, bev);
    k_fallback<<<dim3(NCOL), dim3(BEVC), 0, stream>>>(fpb, dpb, Km, Tm, trust, depths, cellidx, bev);

    // BEV refinement convs (MFMA): fp32 -> bf16, then bf16 -> fp32
    k_bevconv<0, 1><<<dim3(BEVW / TX2, BEVH / TY2, BQ), dim3(256), 0, stream>>>(bev, wf1, br_b1, h2b);
    k_bevconv<1, 0><<<dim3(BEVW / TX2, BEVH / TY2, BQ), dim3(256), 0, stream>>>(h2b, wf2, br_b2, o2);

    // NHWC -> NCHW
    k_to_nchw<<<dim3(4, BEVH, BQ), dim3(256), 0, stream>>>(o2, out);
}

// Round 7
// 728.095 us; speedup vs baseline: 1.1513x; 1.1513x over previous
//
#include <hip/hip_runtime.h>
#include <hip/hip_bf16.h>
#include <math.h>

#define BQ 2
#define NV 6
#define CIN 64
#define HF 32
#define WF 56
#define ND 32
#define BEVC 128
#define BEVH 128
#define BEVW 128
#define NPIX (HF*WF)     // 1792
#define BV (BQ*NV)       // 12
#define NCOL (BV*WF)     // 672
#define NITEM (NCOL*ND)  // 21504
#define NCELL (BQ*BEVH*BEVW) // 32768
#define EXT 20.0f
#define BN_S 0.99999500003749937f

typedef short bf16x8 __attribute__((ext_vector_type(8)));
typedef float f32x4 __attribute__((ext_vector_type(4)));

__device__ __forceinline__ float gelu(float x) {
    return 0.5f * x * (1.0f + erff(x * 0.70710678118654752f));
}

__device__ __forceinline__ unsigned short f2bf(float x) {
    union { float f; unsigned u; } v; v.f = x;
    unsigned r = v.u + 0x7FFFu + ((v.u >> 16) & 1u);
    return (unsigned short)(r >> 16);
}

// ---------------- Kernel 1: 3x3 conv 64->64, *BN_S, gelu. NCHW in/out ----------------
#define COG 16
__global__ void k_conv1(const float* __restrict__ fm, const float* __restrict__ w,
                        const float* __restrict__ bias, float* __restrict__ out) {
    int g   = blockIdx.x * 256 + threadIdx.x;
    int co0 = blockIdx.y * COG;
    int bv  = g / NPIX, pix = g % NPIX;
    int py  = pix / WF, px = pix % WF;
    const float* in0 = fm + (size_t)bv * CIN * NPIX + py * WF + px;

    bool ym[3], xm[3];
    #pragma unroll
    for (int d = 0; d < 3; d++) {
        ym[d] = (unsigned)(py + d - 1) < (unsigned)HF;
        xm[d] = (unsigned)(px + d - 1) < (unsigned)WF;
    }

    float acc[COG];
    #pragma unroll
    for (int c = 0; c < COG; c++) acc[c] = bias[co0 + c];

    for (int ci = 0; ci < CIN; ci++) {
        const float* ip = in0 + ci * NPIX;
        float v[9];
        #pragma unroll
        for (int dy = 0; dy < 3; dy++)
            #pragma unroll
            for (int dx = 0; dx < 3; dx++)
                v[dy * 3 + dx] = (ym[dy] && xm[dx]) ? ip[(dy - 1) * WF + (dx - 1)] : 0.0f;
        const float* wp = w + ((size_t)co0 * CIN + ci) * 9;  // wave-uniform -> s_load
        #pragma unroll
        for (int c = 0; c < COG; c++)
            #pragma unroll
            for (int k = 0; k < 9; k++)
                acc[c] += wp[(size_t)c * CIN * 9 + k] * v[k];
    }

    float* op = out + (size_t)bv * CIN * NPIX + (size_t)co0 * NPIX + pix;
    #pragma unroll
    for (int c = 0; c < COG; c++) op[(size_t)c * NPIX] = gelu(acc[c] * BN_S);
}

// ---------------- Kernel 2: 1x1 conv 64->32 + softmax over 32. out [p][d] ----------------
__global__ void k_depth(const float* __restrict__ h, const float* __restrict__ w,
                        const float* __restrict__ bias, float* __restrict__ dp) {
    __shared__ float wl[ND * CIN];
    __shared__ float bl[ND];
    for (int i = threadIdx.x; i < ND * CIN; i += 256) wl[i] = w[i];
    if (threadIdx.x < ND) bl[threadIdx.x] = bias[threadIdx.x];
    __syncthreads();
    int g = blockIdx.x * 256 + threadIdx.x;
    if (g >= BV * NPIX) return;
    int bv = g / NPIX, pix = g % NPIX;
    float hv[CIN];
    const float* hp = h + (size_t)bv * CIN * NPIX + pix;
    #pragma unroll
    for (int ci = 0; ci < CIN; ci++) hv[ci] = hp[ci * NPIX];
    float o[ND];
    float mx = -1e30f;
    #pragma unroll
    for (int d = 0; d < ND; d++) {
        float acc = bl[d];
        #pragma unroll
        for (int ci = 0; ci < CIN; ci++) acc += wl[d * CIN + ci] * hv[ci];
        o[d] = acc;
        mx = fmaxf(mx, acc);
    }
    float s = 0.f;
    #pragma unroll
    for (int d = 0; d < ND; d++) { o[d] = expf(o[d] - mx); s += o[d]; }
    float inv = 1.0f / s;
    float* op = dp + (size_t)g * ND;
    #pragma unroll
    for (int d = 0; d < ND; d++) op[d] = o[d] * inv;
}

// ---------------- Kernel 3: 1x1 conv 64->128, *BN_S, gelu. out [p][co] ----------------
// block 256 = 128 co x 2 pixel-halves; 16 pixels per block.
// Weights in LDS [ci][co] with +1-padded row (129): coalesced float4 global reads,
// <=2-way-aliased LDS writes (free), conflict-free reads. No per-thread arrays -> no spill.
#define FPPIX 16
__global__ void k_fp(const float* __restrict__ fm, const float* __restrict__ w,
                     const float* __restrict__ bias, float* __restrict__ fp) {
    __shared__ float wl[CIN * 129];      // [ci][co] padded: 33024 B
    __shared__ float il[CIN * FPPIX];    // [ci][pixel]: 4096 B

    // stage weights: w[co][ci] -> wl[ci*129+co]
    for (int i = threadIdx.x; i < CIN * BEVC / 4; i += 256) {
        int co = i >> 4, c4 = i & 15;
        float4 v = ((const float4*)(w + (size_t)co * CIN))[c4];
        wl[(c4 * 4 + 0) * 129 + co] = v.x;
        wl[(c4 * 4 + 1) * 129 + co] = v.y;
        wl[(c4 * 4 + 2) * 129 + co] = v.z;
        wl[(c4 * 4 + 3) * 129 + co] = v.w;
    }

    int p0 = blockIdx.x * FPPIX;          // NPIX % 16 == 0 -> no bv crossing
    int bv = p0 / NPIX, pix = p0 % NPIX;
    const float* ip = fm + (size_t)bv * CIN * NPIX + pix;
    for (int i = threadIdx.x; i < CIN * FPPIX; i += 256) {
        int ci = i >> 4, pl = i & 15;
        il[i] = ip[ci * NPIX + pl];
    }
    __syncthreads();

    int co   = threadIdx.x & 127;
    int half = threadIdx.x >> 7;
    float acc[8];
    float bi = bias[co];
    #pragma unroll
    for (int p = 0; p < 8; p++) acc[p] = bi;

    for (int ci = 0; ci < CIN; ci++) {
        float wv = wl[ci * 129 + co];
        float4 a = ((const float4*)&il[ci * 16 + half * 8])[0];
        float4 b = ((const float4*)&il[ci * 16 + half * 8])[1];
        acc[0] += wv * a.x; acc[1] += wv * a.y; acc[2] += wv * a.z; acc[3] += wv * a.w;
        acc[4] += wv * b.x; acc[5] += wv * b.y; acc[6] += wv * b.z; acc[7] += wv * b.w;
    }
    #pragma unroll
    for (int p = 0; p < 8; p++)
        fp[(size_t)(p0 + half * 8 + p) * BEVC + co] = gelu(acc[p] * BN_S);
}

// ---------------- geometry helper: BEV cell for (bv,px,py,di). Reference op order. ----------------
struct Geo {
    float i00,i01,i02,i10,i11,i12,i20,i21,i22;
    float R00,R01,R02,t0,R10,R11,R12,t1;
};
__device__ __forceinline__ Geo load_geo(const float* Km, const float* Tm, int bv) {
    Geo G;
    const float* Kp = Km + bv * 9;
    float a = Kp[0], bb = Kp[1], cc = Kp[2];
    float d = Kp[3], e  = Kp[4], f  = Kp[5];
    float g = Kp[6], hh = Kp[7], ii = Kp[8];
    float A  = e * ii - f * hh;
    float Bm = -(d * ii - f * g);
    float Cm = d * hh - e * g;
    float det = a * A + bb * Bm + cc * Cm;
    float invd = 1.0f / det;
    G.i00 = A * invd;  G.i01 = -(bb * ii - cc * hh) * invd; G.i02 = (bb * f - cc * e) * invd;
    G.i10 = Bm * invd; G.i11 = (a * ii - cc * g) * invd;    G.i12 = -(a * f - cc * d) * invd;
    G.i20 = Cm * invd; G.i21 = -(a * hh - bb * g) * invd;   G.i22 = (a * e - bb * d) * invd;
    const float* Tp = Tm + bv * 16;
    G.R00 = Tp[0]; G.R01 = Tp[1]; G.R02 = Tp[2]; G.t0 = Tp[3];
    G.R10 = Tp[4]; G.R11 = Tp[5]; G.R12 = Tp[6]; G.t1 = Tp[7];
    return G;
}
__device__ __forceinline__ int geo_cell(const Geo& G, int px, int py, float dep) {
    float fx = (float)px, fy = (float)py;
    float r0 = G.i00 * fx + G.i01 * fy + G.i02;
    float r1 = G.i10 * fx + G.i11 * fy + G.i12;
    float r2 = G.i20 * fx + G.i21 * fy + G.i22;
    float xe = G.R00 * (r0 * dep) + G.R01 * (r1 * dep) + G.R02 * (r2 * dep) + G.t0;
    float ye = G.R10 * (r0 * dep) + G.R11 * (r1 * dep) + G.R12 * (r2 * dep) + G.t1;
    int col = (int)((xe + EXT) / (2.0f * EXT) * (float)(BEVW - 1));
    int row = (int)((ye + EXT) / (2.0f * EXT) * (float)(BEVH - 1));
    return (col >= 0 && col < BEVW && row >= 0 && row < BEVH) ? row * BEVW + col : -1;
}

// ---------------- Kernel 4a: per-column py-pre-reduction -> M rows + cell ids (no atomics) ----
__global__ void k_prered(const float* __restrict__ fp, const float* __restrict__ dp,
                         const float* __restrict__ Km, const float* __restrict__ Tm,
                         const float* __restrict__ trust, const float* __restrict__ depths,
                         float* __restrict__ M, int* __restrict__ cellidx) {
    __shared__ float fpl[HF * BEVC];   // [py][c], pre-scaled by trust
    __shared__ float dpl[HF * ND];     // [py][di]
    __shared__ int   celll[ND * HF];   // [di][py]
    __shared__ int   uni[ND];

    int col = blockIdx.x;
    int bv = col / WF, px = col % WF;
    int b  = bv / NV;
    float tw = trust[bv];

    for (int i = threadIdx.x; i < HF * (BEVC / 4); i += 256) {
        int py = i >> 5, c4 = i & 31;
        float4 v = ((const float4*)(fp + ((size_t)bv * NPIX + py * WF + px) * BEVC))[c4];
        v.x *= tw; v.y *= tw; v.z *= tw; v.w *= tw;
        ((float4*)fpl)[py * 32 + c4] = v;
    }
    for (int i = threadIdx.x; i < HF * (ND / 4); i += 256) {
        int py = i >> 3, d4 = i & 7;
        ((float4*)dpl)[py * 8 + d4] =
            ((const float4*)(dp + ((size_t)bv * NPIX + py * WF + px) * ND))[d4];
    }

    Geo G = load_geo(Km, Tm, bv);
    for (int q = threadIdx.x; q < ND * HF; q += 256) {
        int di = q >> 5, py = q & 31;
        celll[q] = geo_cell(G, px, py, depths[di]);
    }
    __syncthreads();

    if (threadIdx.x < ND) {
        int di = threadIdx.x;
        int c0 = celll[di * HF];
        bool u = true;
        for (int py = 1; py < HF; py++) u &= (celll[di * HF + py] == c0);
        uni[di] = u ? c0 : -2;
    }
    __syncthreads();

    int c = threadIdx.x & 127, dg = threadIdx.x >> 7;
    float acc[16];
    #pragma unroll
    for (int k = 0; k < 16; k++) acc[k] = 0.f;
    for (int py = 0; py < HF; py++) {
        float fv = fpl[py * BEVC + c];
        #pragma unroll
        for (int k = 0; k < 16; k++)
            acc[k] += fv * dpl[py * ND + dg * 16 + k];
    }
    #pragma unroll
    for (int k = 0; k < 16; k++)
        M[((size_t)col * ND + dg * 16 + k) * BEVC + c] = acc[k];

    if (threadIdx.x < ND) {
        int u = uni[threadIdx.x];
        cellidx[col * ND + threadIdx.x] = (u >= 0) ? (b * (BEVH * BEVW) + u) : u;
    }
}

// ---------------- Kernel 4b/c/d: counting sort by cell ----------------
__global__ void k_hist(const int* __restrict__ cellidx, int* __restrict__ count) {
    int i = blockIdx.x * 256 + threadIdx.x;
    if (i >= NITEM) return;
    int c = cellidx[i];
    if (c >= 0) atomicAdd(&count[c], 1);
}

__global__ void k_scan(const int* __restrict__ count, int* __restrict__ offs,
                       int* __restrict__ cursor) {
    __shared__ int part[1024];
    int t = threadIdx.x;
    int base = t * 32;
    int loc[32];
    int s = 0;
    #pragma unroll
    for (int i = 0; i < 32; i++) { loc[i] = s; s += count[base + i]; }
    part[t] = s;
    __syncthreads();
    for (int off = 1; off < 1024; off <<= 1) {
        int v = (t >= off) ? part[t - off] : 0;
        __syncthreads();
        part[t] += v;
        __syncthreads();
    }
    int pre = (t == 0) ? 0 : part[t - 1];
    #pragma unroll
    for (int i = 0; i < 32; i++) {
        offs[base + i] = pre + loc[i];
        cursor[base + i] = pre + loc[i];
    }
    if (t == 1023) offs[NCELL] = pre + s;
}

__global__ void k_fill(const int* __restrict__ cellidx, int* __restrict__ cursor,
                       int* __restrict__ itemlist) {
    int i = blockIdx.x * 256 + threadIdx.x;
    if (i >= NITEM) return;
    int c = cellidx[i];
    if (c >= 0) {
        int p = atomicAdd(&cursor[c], 1);
        itemlist[p] = i;
    }
}

// ---------------- Kernel 4e: gather. block = cell (128 thr = channels). bev written once. ----
__global__ void k_gather(const float* __restrict__ M, const int* __restrict__ offs,
                         const int* __restrict__ itemlist, float* __restrict__ bev) {
    int cell = blockIdx.x;
    int s = offs[cell], e = offs[cell + 1];
    int c = threadIdx.x;
    float acc = 0.f;
    for (int j = s; j < e; j++) {
        int it = itemlist[j];               // wave-uniform scalar load
        acc += M[(size_t)it * BEVC + c];
    }
    bev[(size_t)cell * BEVC + c] = acc;
}

// ---------------- Kernel 4f: generic fallback for non-uniform columns (normally no-op) ----
__global__ void k_fallback(const float* __restrict__ fp, const float* __restrict__ dp,
                           const float* __restrict__ Km, const float* __restrict__ Tm,
                           const float* __restrict__ trust, const float* __restrict__ depths,
                           const int* __restrict__ cellidx, float* __restrict__ bev) {
    int col = blockIdx.x;
    bool any = false;
    for (int di = 0; di < ND; di++) any |= (cellidx[col * ND + di] == -2);
    if (!any) return;

    int bv = col / WF, px = col % WF;
    int b  = bv / NV;
    float tw = trust[bv];
    Geo G = load_geo(Km, Tm, bv);
    int c = threadIdx.x;
    float* bevb = bev + (size_t)b * BEVH * BEVW * BEVC;
    for (int di = 0; di < ND; di++) {
        if (cellidx[col * ND + di] != -2) continue;
        float dep = depths[di];
        for (int py = 0; py < HF; py++) {
            int cell = geo_cell(G, px, py, dep);
            if (cell >= 0) {
                float v = fp[((size_t)bv * NPIX + py * WF + px) * BEVC + c] * tw *
                          dp[((size_t)bv * NPIX + py * WF + px) * ND + di];
                atomicAdd(&bevb[(size_t)cell * BEVC + c], v);
            }
        }
    }
}

// ---------------- weight prep: w[co][ci][3][3] fp32 -> fragment-linear bf16 ----------------
__global__ void k_wprep(const float* __restrict__ w, unsigned short* __restrict__ wf) {
    int i = blockIdx.x * 256 + threadIdx.x;
    if (i >= 9 * 4 * 8 * 64 * 8) return;
    int e     = i & 7;
    int lane  = (i >> 3) & 63;
    int ntile = (i >> 9) & 7;
    int kstep = (i >> 12) & 3;
    int kpos  = i >> 14;
    int co = ntile * 16 + (lane & 15);
    int ci = kstep * 32 + ((lane >> 4) << 3) + e;
    wf[i] = f2bf(w[((size_t)co * BEVC + ci) * 9 + kpos]);
}

// ---------------- Kernel 5/6: 3x3 conv 128->128 NHWC via MFMA bf16 ----------------
#define TX2 16
#define TY2 4
#define HALO_W 18
#define HALO_H 6
#define HP (HALO_W*HALO_H)   // 108

__device__ __forceinline__ int swz(int pix, int off) {
    return pix * 256 + (off ^ ((pix & 7) << 4));
}

template<int TI_BF, int TO_BF>
__global__ void k_bevconv(const void* __restrict__ in_, const unsigned short* __restrict__ wfrag,
                          const float* __restrict__ bias, void* __restrict__ out_) {
    __shared__ char ldsb[HP * 256];   // [pix(108)][ci(128) bf16], XOR-swizzled
    int x0 = blockIdx.x * TX2;
    int y0 = blockIdx.y * TY2;
    int b  = blockIdx.z;

    for (int t = threadIdx.x; t < HP * 16; t += 256) {
        int pix = t >> 4, oct = t & 15;
        int r = pix / HALO_W, c = pix % HALO_W;
        int gy = y0 + r - 1, gx = x0 + c - 1;
        int4 w4 = {0, 0, 0, 0};
        if ((unsigned)gy < (unsigned)BEVH && (unsigned)gx < (unsigned)BEVW) {
            size_t base = ((size_t)(b * BEVH + gy) * BEVW + gx) * BEVC + oct * 8;
            if (TI_BF) {
                w4 = *(const int4*)((const unsigned short*)in_ + base);
            } else {
                const float* p = (const float*)in_ + base;
                float4 f0 = ((const float4*)p)[0];
                float4 f1 = ((const float4*)p)[1];
                w4.x = f2bf(f0.x) | ((int)f2bf(f0.y) << 16);
                w4.y = f2bf(f0.z) | ((int)f2bf(f0.w) << 16);
                w4.z = f2bf(f1.x) | ((int)f2bf(f1.y) << 16);
                w4.w = f2bf(f1.z) | ((int)f2bf(f1.w) << 16);
            }
        }
        *(int4*)(ldsb + swz(pix, oct * 16)) = w4;
    }
    __syncthreads();

    int wave = threadIdx.x >> 6;
    int lane = threadIdx.x & 63;
    int xx   = lane & 15;
    int kgrp = lane >> 4;

    const bf16x8* wv = (const bf16x8*)wfrag;

    f32x4 acc[TY2][2];
    {
        float b0 = bias[wave * 32 + (lane & 15)];
        float b1 = bias[wave * 32 + 16 + (lane & 15)];
        #pragma unroll
        for (int m = 0; m < TY2; m++) {
            acc[m][0] = (f32x4){b0, b0, b0, b0};
            acc[m][1] = (f32x4){b1, b1, b1, b1};
        }
    }

    for (int kpos = 0; kpos < 9; kpos++) {
        int dy = kpos / 3, dx = kpos % 3;
        #pragma unroll
        for (int kstep = 0; kstep < 4; kstep++) {
            bf16x8 bf0 = wv[((kpos * 4 + kstep) * 8 + wave * 2 + 0) * 64 + lane];
            bf16x8 bf1 = wv[((kpos * 4 + kstep) * 8 + wave * 2 + 1) * 64 + lane];
            #pragma unroll
            for (int m = 0; m < TY2; m++) {
                bf16x8 a = *(const bf16x8*)(ldsb + swz((m + dy) * HALO_W + xx + dx,
                                                       kstep * 64 + kgrp * 16));
                acc[m][0] = __builtin_amdgcn_mfma_f32_16x16x32_bf16(a, bf0, acc[m][0], 0, 0, 0);
                acc[m][1] = __builtin_amdgcn_mfma_f32_16x16x32_bf16(a, bf1, acc[m][1], 0, 0, 0);
            }
        }
    }

    #pragma unroll
    for (int m = 0; m < TY2; m++) {
        int gy = y0 + m;
        #pragma unroll
        for (int n = 0; n < 2; n++) {
            int co = wave * 32 + n * 16 + (lane & 15);
            #pragma unroll
            for (int r = 0; r < 4; r++) {
                int gx = x0 + kgrp * 4 + r;
                float v = gelu(acc[m][n][r] * BN_S);
                size_t oi = ((size_t)(b * BEVH + gy) * BEVW + gx) * BEVC + co;
                if (TO_BF) ((unsigned short*)out_)[oi] = f2bf(v);
                else       ((float*)out_)[oi] = v;
            }
        }
    }
}

// ---------------- NHWC -> NCHW transpose for final output ----------------
__global__ void k_to_nchw(const float* __restrict__ in, float* __restrict__ out) {
    __shared__ float t[64][65];
    int b = blockIdx.z;
    int y = blockIdx.y;
    int xt = (blockIdx.x & 1) * 64;
    int ct = (blockIdx.x >> 1) * 64;
    int lc = threadIdx.x & 63;
    int lr = threadIdx.x >> 6;
    #pragma unroll
    for (int i = 0; i < 16; i++) {
        int xi = lr + i * 4;
        t[xi][lc] = in[(((size_t)b * BEVH + y) * BEVW + xt + xi) * BEVC + ct + lc];
    }
    __syncthreads();
    #pragma unroll
    for (int i = 0; i < 16; i++) {
        int ci = lr + i * 4;
        out[(((size_t)b * BEVC + ct + ci) * BEVH + y) * BEVW + xt + lc] = t[lc][ci];
    }
}

extern "C" void kernel_launch(void* const* d_in, const int* in_sizes, int n_in,
                              void* d_out, int out_size, void* d_ws, size_t ws_size,
                              hipStream_t stream) {
    const float* feat_maps = (const float*)d_in[0];
    const float* Km        = (const float*)d_in[1];
    const float* Tm        = (const float*)d_in[2];
    const float* trust     = (const float*)d_in[3];
    const float* depths    = (const float*)d_in[4];
    const float* dh_w1     = (const float*)d_in[5];
    const float* dh_b1     = (const float*)d_in[6];
    const float* dh_w2     = (const float*)d_in[7];
    const float* dh_b2     = (const float*)d_in[8];
    const float* fp_w      = (const float*)d_in[9];
    const float* fp_b      = (const float*)d_in[10];
    const float* br_w1     = (const float*)d_in[11];
    const float* br_b1     = (const float*)d_in[12];
    const float* br_w2     = (const float*)d_in[13];
    const float* br_b2     = (const float*)d_in[14];
    float* out = (float*)d_out;

    float* ws  = (float*)d_ws;
    float* h1  = ws;                                     // 12*64*1792 f
    float* dpb = h1 + (size_t)BV * CIN * NPIX;           // 12*1792*32 f
    float* fpb = dpb + (size_t)BV * NPIX * ND;           // 12*1792*128 f
    float* bev = fpb + (size_t)BV * NPIX * BEVC;         // 2*16384*128 f
    float* o2  = bev + (size_t)BQ * BEVH * BEVW * BEVC;  // 2*16384*128 f
    float* Mb  = o2 + (size_t)BQ * BEVH * BEVW * BEVC;   // 21504*128 f
    unsigned short* h2b = (unsigned short*)(Mb + (size_t)NITEM * BEVC); // bf16, NCELL*128
    unsigned short* wf1 = h2b + (size_t)BQ * BEVH * BEVW * BEVC;
    unsigned short* wf2 = wf1 + (size_t)9 * 4 * 8 * 64 * 8;
    int* cellidx  = (int*)(wf2 + (size_t)9 * 4 * 8 * 64 * 8); // NITEM
    int* count    = cellidx + NITEM;        // NCELL
    int* offs     = count + NCELL;          // NCELL+1
    int* cursor   = offs + NCELL + 1;       // NCELL
    int* itemlist = cursor + NCELL;         // NITEM

    // weight prep (fragment-linear bf16)
    k_wprep<<<dim3((9 * 4 * 8 * 64 * 8 + 255) / 256), dim3(256), 0, stream>>>(br_w1, wf1);
    k_wprep<<<dim3((9 * 4 * 8 * 64 * 8 + 255) / 256), dim3(256), 0, stream>>>(br_w2, wf2);

    // depth-head conv1 + gelu
    k_conv1<<<dim3(BV * NPIX / 256, CIN / COG), dim3(256), 0, stream>>>(feat_maps, dh_w1, dh_b1, h1);

    // depth probs
    k_depth<<<dim3(BV * NPIX / 256), dim3(256), 0, stream>>>(h1, dh_w2, dh_b2, dpb);

    // feature projection
    k_fp<<<dim3(BV * NPIX / FPPIX), dim3(256), 0, stream>>>(feat_maps, fp_w, fp_b, fpb);

    // --- scatter via sort+gather (no fp32 atomics) ---
    k_prered<<<dim3(NCOL), dim3(256), 0, stream>>>(fpb, dpb, Km, Tm, trust, depths, Mb, cellidx);
    hipMemsetAsync(count, 0, NCELL * sizeof(int), stream);
    k_hist<<<dim3((NITEM + 255) / 256), dim3(256), 0, stream>>>(cellidx, count);
    k_scan<<<dim3(1), dim3(1024), 0, stream>>>(count, offs, cursor);
    k_fill<<<dim3((NITEM + 255) / 256), dim3(256), 0, stream>>>(cellidx, cursor, itemlist);
    k_gather<<<dim3(NCELL), dim3(BEVC), 0, stream>>>(Mb, offs, itemlist, bev);
    k_fallback<<<dim3(NCOL), dim3(BEVC), 0, stream>>>(fpb, dpb, Km, Tm, trust, depths, cellidx, bev);

    // BEV refinement convs (MFMA): fp32 -> bf16, then bf16 -> fp32
    k_bevconv<0, 1><<<dim3(BEVW / TX2, BEVH / TY2, BQ), dim3(256), 0, stream>>>(bev, wf1, br_b1, h2b);
    k_bevconv<1, 0><<<dim3(BEVW / TX2, BEVH / TY2, BQ), dim3(256), 0, stream>>>(h2b, wf2, br_b2, o2);

    // NHWC -> NCHW
    k_to_nchw<<<dim3(4, BEVH, BQ), dim3(256), 0, stream>>>(o2, out);
}

// Round 8
// 251.379 us; speedup vs baseline: 3.3346x; 2.8964x over previous
//
#include <hip/hip_runtime.h>
#include <hip/hip_bf16.h>
#include <math.h>

#define BQ 2
#define NV 6
#define CIN 64
#define HF 32
#define WF 56
#define ND 32
#define BEVC 128
#define BEVH 128
#define BEVW 128
#define NPIX (HF*WF)     // 1792
#define BV (BQ*NV)       // 12
#define NCOL (BV*WF)     // 672
#define NITEM (NCOL*ND)  // 21504
#define NCELL (BQ*BEVH*BEVW) // 32768
#define EXT 20.0f
#define BN_S 0.99999500003749937f

typedef short bf16x8 __attribute__((ext_vector_type(8)));
typedef float f32x4 __attribute__((ext_vector_type(4)));

__device__ __forceinline__ float gelu(float x) {
    return 0.5f * x * (1.0f + erff(x * 0.70710678118654752f));
}

__device__ __forceinline__ unsigned short f2bf(float x) {
    union { float f; unsigned u; } v; v.f = x;
    unsigned r = v.u + 0x7FFFu + ((v.u >> 16) & 1u);
    return (unsigned short)(r >> 16);
}

// ---------------- Kernel 1: 3x3 conv 64->64, *BN_S, gelu. NCHW in/out ----------------
#define COG 16
__global__ void k_conv1(const float* __restrict__ fm, const float* __restrict__ w,
                        const float* __restrict__ bias, float* __restrict__ out) {
    int g   = blockIdx.x * 256 + threadIdx.x;
    int co0 = blockIdx.y * COG;
    int bv  = g / NPIX, pix = g % NPIX;
    int py  = pix / WF, px = pix % WF;
    const float* in0 = fm + (size_t)bv * CIN * NPIX + py * WF + px;

    bool ym[3], xm[3];
    #pragma unroll
    for (int d = 0; d < 3; d++) {
        ym[d] = (unsigned)(py + d - 1) < (unsigned)HF;
        xm[d] = (unsigned)(px + d - 1) < (unsigned)WF;
    }

    float acc[COG];
    #pragma unroll
    for (int c = 0; c < COG; c++) acc[c] = bias[co0 + c];

    for (int ci = 0; ci < CIN; ci++) {
        const float* ip = in0 + ci * NPIX;
        float v[9];
        #pragma unroll
        for (int dy = 0; dy < 3; dy++)
            #pragma unroll
            for (int dx = 0; dx < 3; dx++)
                v[dy * 3 + dx] = (ym[dy] && xm[dx]) ? ip[(dy - 1) * WF + (dx - 1)] : 0.0f;
        const float* wp = w + ((size_t)co0 * CIN + ci) * 9;  // wave-uniform -> s_load
        #pragma unroll
        for (int c = 0; c < COG; c++)
            #pragma unroll
            for (int k = 0; k < 9; k++)
                acc[c] += wp[(size_t)c * CIN * 9 + k] * v[k];
    }

    float* op = out + (size_t)bv * CIN * NPIX + (size_t)co0 * NPIX + pix;
    #pragma unroll
    for (int c = 0; c < COG; c++) op[(size_t)c * NPIX] = gelu(acc[c] * BN_S);
}

// ---------------- Kernel 2: 1x1 conv 64->32 + softmax over 32. out [p][d] ----------------
__global__ void k_depth(const float* __restrict__ h, const float* __restrict__ w,
                        const float* __restrict__ bias, float* __restrict__ dp) {
    __shared__ float wl[ND * CIN];
    __shared__ float bl[ND];
    for (int i = threadIdx.x; i < ND * CIN; i += 256) wl[i] = w[i];
    if (threadIdx.x < ND) bl[threadIdx.x] = bias[threadIdx.x];
    __syncthreads();
    int g = blockIdx.x * 256 + threadIdx.x;
    if (g >= BV * NPIX) return;
    int bv = g / NPIX, pix = g % NPIX;
    float hv[CIN];
    const float* hp = h + (size_t)bv * CIN * NPIX + pix;
    #pragma unroll
    for (int ci = 0; ci < CIN; ci++) hv[ci] = hp[ci * NPIX];
    float o[ND];
    float mx = -1e30f;
    #pragma unroll
    for (int d = 0; d < ND; d++) {
        float acc = bl[d];
        #pragma unroll
        for (int ci = 0; ci < CIN; ci++) acc += wl[d * CIN + ci] * hv[ci];
        o[d] = acc;
        mx = fmaxf(mx, acc);
    }
    float s = 0.f;
    #pragma unroll
    for (int d = 0; d < ND; d++) { o[d] = expf(o[d] - mx); s += o[d]; }
    float inv = 1.0f / s;
    float* op = dp + (size_t)g * ND;
    #pragma unroll
    for (int d = 0; d < ND; d++) op[d] = o[d] * inv;
}

// ---------------- fp weight prep: w[co][ci] fp32 -> fragment-linear bf16 ----------------
// layout [kstep(2)][ntile(8)][lane(64)][e(8)]; co=ntile*16+(lane&15), ci=kstep*32+(lane>>4)*8+e
__global__ void k_wprep_fp(const float* __restrict__ w, unsigned short* __restrict__ wf) {
    int i = blockIdx.x * 256 + threadIdx.x;
    if (i >= 2 * 8 * 64 * 8) return;
    int e     = i & 7;
    int lane  = (i >> 3) & 63;
    int ntile = (i >> 9) & 7;
    int kstep = (i >> 12) & 1;
    int co = ntile * 16 + (lane & 15);
    int ci = kstep * 32 + ((lane >> 4) << 3) + e;
    wf[i] = f2bf(w[(size_t)co * CIN + ci]);
}

// ---------------- Kernel 3: 1x1 conv 64->128 via MFMA bf16. out [pix][co] ----------------
// block 256 (4 waves), 64 pixels per block (wave: 16 pixels x 128 co). NPIX%64==0.
__global__ void k_fp(const float* __restrict__ fm, const unsigned short* __restrict__ wfrag,
                     const float* __restrict__ bias, float* __restrict__ fp) {
    __shared__ char als[64 * 128];   // [pix(64)][ci(64) bf16], XOR-swizzled
    int p0 = blockIdx.x * 64;
    int bv = p0 / NPIX, pl0 = p0 % NPIX;
    const float* fmb = fm + (size_t)bv * CIN * NPIX + pl0;

    // stage 64 pix x 64 ci -> bf16 LDS. Per wave: 8 coalesced 256B row reads.
    #pragma unroll
    for (int it = 0; it < 2; it++) {
        int t = threadIdx.x + it * 256;
        int oct = t >> 6, pix = t & 63;
        unsigned short b8[8];
        #pragma unroll
        for (int j = 0; j < 8; j++)
            b8[j] = f2bf(fmb[(size_t)(oct * 8 + j) * NPIX + pix]);
        int4 w4;
        w4.x = b8[0] | ((int)b8[1] << 16);
        w4.y = b8[2] | ((int)b8[3] << 16);
        w4.z = b8[4] | ((int)b8[5] << 16);
        w4.w = b8[6] | ((int)b8[7] << 16);
        *(int4*)(als + pix * 128 + ((oct * 16) ^ ((pix & 7) << 4))) = w4;
    }
    __syncthreads();

    int wave = threadIdx.x >> 6;
    int lane = threadIdx.x & 63;
    int xx   = lane & 15;      // A-row / D-col index
    int kgrp = lane >> 4;

    int prow = wave * 16 + xx; // pixel for A-fragment
    bf16x8 a0 = *(const bf16x8*)(als + prow * 128 + ((       kgrp * 16) ^ ((prow & 7) << 4)));
    bf16x8 a1 = *(const bf16x8*)(als + prow * 128 + ((64  +  kgrp * 16) ^ ((prow & 7) << 4)));

    const bf16x8* wv = (const bf16x8*)wfrag;

    #pragma unroll
    for (int n = 0; n < 8; n++) {
        float bi = bias[n * 16 + xx];
        f32x4 acc = (f32x4){bi, bi, bi, bi};
        bf16x8 b0 = wv[(0 * 8 + n) * 64 + lane];
        bf16x8 b1 = wv[(1 * 8 + n) * 64 + lane];
        acc = __builtin_amdgcn_mfma_f32_16x16x32_bf16(a0, b0, acc, 0, 0, 0);
        acc = __builtin_amdgcn_mfma_f32_16x16x32_bf16(a1, b1, acc, 0, 0, 0);
        // D: col = lane&15 (co in tile), row = kgrp*4 + r (pixel in 16-tile)
        #pragma unroll
        for (int r = 0; r < 4; r++) {
            int pixel = wave * 16 + kgrp * 4 + r;
            fp[(size_t)(p0 + pixel) * BEVC + n * 16 + xx] = gelu(acc[r] * BN_S);
        }
    }
}

// ---------------- geometry helper: BEV cell for (bv,px,py,di). Reference op order. ----------------
struct Geo {
    float i00,i01,i02,i10,i11,i12,i20,i21,i22;
    float R00,R01,R02,t0,R10,R11,R12,t1;
};
__device__ __forceinline__ Geo load_geo(const float* Km, const float* Tm, int bv) {
    Geo G;
    const float* Kp = Km + bv * 9;
    float a = Kp[0], bb = Kp[1], cc = Kp[2];
    float d = Kp[3], e  = Kp[4], f  = Kp[5];
    float g = Kp[6], hh = Kp[7], ii = Kp[8];
    float A  = e * ii - f * hh;
    float Bm = -(d * ii - f * g);
    float Cm = d * hh - e * g;
    float det = a * A + bb * Bm + cc * Cm;
    float invd = 1.0f / det;
    G.i00 = A * invd;  G.i01 = -(bb * ii - cc * hh) * invd; G.i02 = (bb * f - cc * e) * invd;
    G.i10 = Bm * invd; G.i11 = (a * ii - cc * g) * invd;    G.i12 = -(a * f - cc * d) * invd;
    G.i20 = Cm * invd; G.i21 = -(a * hh - bb * g) * invd;   G.i22 = (a * e - bb * d) * invd;
    const float* Tp = Tm + bv * 16;
    G.R00 = Tp[0]; G.R01 = Tp[1]; G.R02 = Tp[2]; G.t0 = Tp[3];
    G.R10 = Tp[4]; G.R11 = Tp[5]; G.R12 = Tp[6]; G.t1 = Tp[7];
    return G;
}
__device__ __forceinline__ int geo_cell(const Geo& G, int px, int py, float dep) {
    float fx = (float)px, fy = (float)py;
    float r0 = G.i00 * fx + G.i01 * fy + G.i02;
    float r1 = G.i10 * fx + G.i11 * fy + G.i12;
    float r2 = G.i20 * fx + G.i21 * fy + G.i22;
    float xe = G.R00 * (r0 * dep) + G.R01 * (r1 * dep) + G.R02 * (r2 * dep) + G.t0;
    float ye = G.R10 * (r0 * dep) + G.R11 * (r1 * dep) + G.R12 * (r2 * dep) + G.t1;
    int col = (int)((xe + EXT) / (2.0f * EXT) * (float)(BEVW - 1));
    int row = (int)((ye + EXT) / (2.0f * EXT) * (float)(BEVH - 1));
    return (col >= 0 && col < BEVW && row >= 0 && row < BEVH) ? row * BEVW + col : -1;
}

// ---------------- Kernel 4a: per-column py-pre-reduction -> M rows + cell ids (no atomics) ----
__global__ void k_prered(const float* __restrict__ fp, const float* __restrict__ dp,
                         const float* __restrict__ Km, const float* __restrict__ Tm,
                         const float* __restrict__ trust, const float* __restrict__ depths,
                         float* __restrict__ M, int* __restrict__ cellidx) {
    __shared__ float fpl[HF * BEVC];   // [py][c], pre-scaled by trust
    __shared__ float dpl[HF * ND];     // [py][di]
    __shared__ int   celll[ND * HF];   // [di][py]
    __shared__ int   uni[ND];

    int col = blockIdx.x;
    int bv = col / WF, px = col % WF;
    int b  = bv / NV;
    float tw = trust[bv];

    for (int i = threadIdx.x; i < HF * (BEVC / 4); i += 256) {
        int py = i >> 5, c4 = i & 31;
        float4 v = ((const float4*)(fp + ((size_t)bv * NPIX + py * WF + px) * BEVC))[c4];
        v.x *= tw; v.y *= tw; v.z *= tw; v.w *= tw;
        ((float4*)fpl)[py * 32 + c4] = v;
    }
    for (int i = threadIdx.x; i < HF * (ND / 4); i += 256) {
        int py = i >> 3, d4 = i & 7;
        ((float4*)dpl)[py * 8 + d4] =
            ((const float4*)(dp + ((size_t)bv * NPIX + py * WF + px) * ND))[d4];
    }

    Geo G = load_geo(Km, Tm, bv);
    for (int q = threadIdx.x; q < ND * HF; q += 256) {
        int di = q >> 5, py = q & 31;
        celll[q] = geo_cell(G, px, py, depths[di]);
    }
    __syncthreads();

    if (threadIdx.x < ND) {
        int di = threadIdx.x;
        int c0 = celll[di * HF];
        bool u = true;
        for (int py = 1; py < HF; py++) u &= (celll[di * HF + py] == c0);
        uni[di] = u ? c0 : -2;
    }
    __syncthreads();

    int c = threadIdx.x & 127, dg = threadIdx.x >> 7;
    float acc[16];
    #pragma unroll
    for (int k = 0; k < 16; k++) acc[k] = 0.f;
    for (int py = 0; py < HF; py++) {
        float fv = fpl[py * BEVC + c];
        #pragma unroll
        for (int k = 0; k < 16; k++)
            acc[k] += fv * dpl[py * ND + dg * 16 + k];
    }
    #pragma unroll
    for (int k = 0; k < 16; k++)
        M[((size_t)col * ND + dg * 16 + k) * BEVC + c] = acc[k];

    if (threadIdx.x < ND) {
        int u = uni[threadIdx.x];
        cellidx[col * ND + threadIdx.x] = (u >= 0) ? (b * (BEVH * BEVW) + u) : u;
    }
}

// ---------------- Kernel 4b/c/d: counting sort by cell ----------------
__global__ void k_hist(const int* __restrict__ cellidx, int* __restrict__ count) {
    int i = blockIdx.x * 256 + threadIdx.x;
    if (i >= NITEM) return;
    int c = cellidx[i];
    if (c >= 0) atomicAdd(&count[c], 1);
}

__global__ void k_scan(const int* __restrict__ count, int* __restrict__ offs,
                       int* __restrict__ cursor) {
    __shared__ int part[1024];
    int t = threadIdx.x;
    int base = t * 32;
    int loc[32];
    int s = 0;
    #pragma unroll
    for (int i = 0; i < 32; i++) { loc[i] = s; s += count[base + i]; }
    part[t] = s;
    __syncthreads();
    for (int off = 1; off < 1024; off <<= 1) {
        int v = (t >= off) ? part[t - off] : 0;
        __syncthreads();
        part[t] += v;
        __syncthreads();
    }
    int pre = (t == 0) ? 0 : part[t - 1];
    #pragma unroll
    for (int i = 0; i < 32; i++) {
        offs[base + i] = pre + loc[i];
        cursor[base + i] = pre + loc[i];
    }
    if (t == 1023) offs[NCELL] = pre + s;
}

__global__ void k_fill(const int* __restrict__ cellidx, int* __restrict__ cursor,
                       int* __restrict__ itemlist) {
    int i = blockIdx.x * 256 + threadIdx.x;
    if (i >= NITEM) return;
    int c = cellidx[i];
    if (c >= 0) {
        int p = atomicAdd(&cursor[c], 1);
        itemlist[p] = i;
    }
}

// ---------------- Kernel 4e: gather. block = cell (128 thr = channels). bev written once. ----
__global__ void k_gather(const float* __restrict__ M, const int* __restrict__ offs,
                         const int* __restrict__ itemlist, float* __restrict__ bev) {
    int cell = blockIdx.x;
    int s = offs[cell], e = offs[cell + 1];
    int c = threadIdx.x;
    float acc = 0.f;
    for (int j = s; j < e; j++) {
        int it = itemlist[j];               // wave-uniform scalar load
        acc += M[(size_t)it * BEVC + c];
    }
    bev[(size_t)cell * BEVC + c] = acc;
}

// ---------------- Kernel 4f: generic fallback for non-uniform columns (normally no-op) ----
__global__ void k_fallback(const float* __restrict__ fp, const float* __restrict__ dp,
                           const float* __restrict__ Km, const float* __restrict__ Tm,
                           const float* __restrict__ trust, const float* __restrict__ depths,
                           const int* __restrict__ cellidx, float* __restrict__ bev) {
    int col = blockIdx.x;
    bool any = false;
    for (int di = 0; di < ND; di++) any |= (cellidx[col * ND + di] == -2);
    if (!any) return;

    int bv = col / WF, px = col % WF;
    int b  = bv / NV;
    float tw = trust[bv];
    Geo G = load_geo(Km, Tm, bv);
    int c = threadIdx.x;
    float* bevb = bev + (size_t)b * BEVH * BEVW * BEVC;
    for (int di = 0; di < ND; di++) {
        if (cellidx[col * ND + di] != -2) continue;
        float dep = depths[di];
        for (int py = 0; py < HF; py++) {
            int cell = geo_cell(G, px, py, dep);
            if (cell >= 0) {
                float v = fp[((size_t)bv * NPIX + py * WF + px) * BEVC + c] * tw *
                          dp[((size_t)bv * NPIX + py * WF + px) * ND + di];
                atomicAdd(&bevb[(size_t)cell * BEVC + c], v);
            }
        }
    }
}

// ---------------- weight prep: w[co][ci][3][3] fp32 -> fragment-linear bf16 ----------------
__global__ void k_wprep(const float* __restrict__ w, unsigned short* __restrict__ wf) {
    int i = blockIdx.x * 256 + threadIdx.x;
    if (i >= 9 * 4 * 8 * 64 * 8) return;
    int e     = i & 7;
    int lane  = (i >> 3) & 63;
    int ntile = (i >> 9) & 7;
    int kstep = (i >> 12) & 3;
    int kpos  = i >> 14;
    int co = ntile * 16 + (lane & 15);
    int ci = kstep * 32 + ((lane >> 4) << 3) + e;
    wf[i] = f2bf(w[((size_t)co * BEVC + ci) * 9 + kpos]);
}

// ---------------- Kernel 5/6: 3x3 conv 128->128 NHWC via MFMA bf16 ----------------
#define TX2 16
#define TY2 4
#define HALO_W 18
#define HALO_H 6
#define HP (HALO_W*HALO_H)   // 108

__device__ __forceinline__ int swz(int pix, int off) {
    return pix * 256 + (off ^ ((pix & 7) << 4));
}

template<int TI_BF, int TO_BF>
__global__ void k_bevconv(const void* __restrict__ in_, const unsigned short* __restrict__ wfrag,
                          const float* __restrict__ bias, void* __restrict__ out_) {
    __shared__ char ldsb[HP * 256];   // [pix(108)][ci(128) bf16], XOR-swizzled
    int x0 = blockIdx.x * TX2;
    int y0 = blockIdx.y * TY2;
    int b  = blockIdx.z;

    for (int t = threadIdx.x; t < HP * 16; t += 256) {
        int pix = t >> 4, oct = t & 15;
        int r = pix / HALO_W, c = pix % HALO_W;
        int gy = y0 + r - 1, gx = x0 + c - 1;
        int4 w4 = {0, 0, 0, 0};
        if ((unsigned)gy < (unsigned)BEVH && (unsigned)gx < (unsigned)BEVW) {
            size_t base = ((size_t)(b * BEVH + gy) * BEVW + gx) * BEVC + oct * 8;
            if (TI_BF) {
                w4 = *(const int4*)((const unsigned short*)in_ + base);
            } else {
                const float* p = (const float*)in_ + base;
                float4 f0 = ((const float4*)p)[0];
                float4 f1 = ((const float4*)p)[1];
                w4.x = f2bf(f0.x) | ((int)f2bf(f0.y) << 16);
                w4.y = f2bf(f0.z) | ((int)f2bf(f0.w) << 16);
                w4.z = f2bf(f1.x) | ((int)f2bf(f1.y) << 16);
                w4.w = f2bf(f1.z) | ((int)f2bf(f1.w) << 16);
            }
        }
        *(int4*)(ldsb + swz(pix, oct * 16)) = w4;
    }
    __syncthreads();

    int wave = threadIdx.x >> 6;
    int lane = threadIdx.x & 63;
    int xx   = lane & 15;
    int kgrp = lane >> 4;

    const bf16x8* wv = (const bf16x8*)wfrag;

    f32x4 acc[TY2][2];
    {
        float b0 = bias[wave * 32 + (lane & 15)];
        float b1 = bias[wave * 32 + 16 + (lane & 15)];
        #pragma unroll
        for (int m = 0; m < TY2; m++) {
            acc[m][0] = (f32x4){b0, b0, b0, b0};
            acc[m][1] = (f32x4){b1, b1, b1, b1};
        }
    }

    for (int kpos = 0; kpos < 9; kpos++) {
        int dy = kpos / 3, dx = kpos % 3;
        #pragma unroll
        for (int kstep = 0; kstep < 4; kstep++) {
            bf16x8 bf0 = wv[((kpos * 4 + kstep) * 8 + wave * 2 + 0) * 64 + lane];
            bf16x8 bf1 = wv[((kpos * 4 + kstep) * 8 + wave * 2 + 1) * 64 + lane];
            #pragma unroll
            for (int m = 0; m < TY2; m++) {
                bf16x8 a = *(const bf16x8*)(ldsb + swz((m + dy) * HALO_W + xx + dx,
                                                       kstep * 64 + kgrp * 16));
                acc[m][0] = __builtin_amdgcn_mfma_f32_16x16x32_bf16(a, bf0, acc[m][0], 0, 0, 0);
                acc[m][1] = __builtin_amdgcn_mfma_f32_16x16x32_bf16(a, bf1, acc[m][1], 0, 0, 0);
            }
        }
    }

    #pragma unroll
    for (int m = 0; m < TY2; m++) {
        int gy = y0 + m;
        #pragma unroll
        for (int n = 0; n < 2; n++) {
            int co = wave * 32 + n * 16 + (lane & 15);
            #pragma unroll
            for (int r = 0; r < 4; r++) {
                int gx = x0 + kgrp * 4 + r;
                float v = gelu(acc[m][n][r] * BN_S);
                size_t oi = ((size_t)(b * BEVH + gy) * BEVW + gx) * BEVC + co;
                if (TO_BF) ((unsigned short*)out_)[oi] = f2bf(v);
                else       ((float*)out_)[oi] = v;
            }
        }
    }
}

// ---------------- NHWC -> NCHW transpose for final output ----------------
__global__ void k_to_nchw(const float* __restrict__ in, float* __restrict__ out) {
    __shared__ float t[64][65];
    int b = blockIdx.z;
    int y = blockIdx.y;
    int xt = (blockIdx.x & 1) * 64;
    int ct = (blockIdx.x >> 1) * 64;
    int lc = threadIdx.x & 63;
    int lr = threadIdx.x >> 6;
    #pragma unroll
    for (int i = 0; i < 16; i++) {
        int xi = lr + i * 4;
        t[xi][lc] = in[(((size_t)b * BEVH + y) * BEVW + xt + xi) * BEVC + ct + lc];
    }
    __syncthreads();
    #pragma unroll
    for (int i = 0; i < 16; i++) {
        int ci = lr + i * 4;
        out[(((size_t)b * BEVC + ct + ci) * BEVH + y) * BEVW + xt + lc] = t[lc][ci];
    }
}

extern "C" void kernel_launch(void* const* d_in, const int* in_sizes, int n_in,
                              void* d_out, int out_size, void* d_ws, size_t ws_size,
                              hipStream_t stream) {
    const float* feat_maps = (const float*)d_in[0];
    const float* Km        = (const float*)d_in[1];
    const float* Tm        = (const float*)d_in[2];
    const float* trust     = (const float*)d_in[3];
    const float* depths    = (const float*)d_in[4];
    const float* dh_w1     = (const float*)d_in[5];
    const float* dh_b1     = (const float*)d_in[6];
    const float* dh_w2     = (const float*)d_in[7];
    const float* dh_b2     = (const float*)d_in[8];
    const float* fp_w      = (const float*)d_in[9];
    const float* fp_b      = (const float*)d_in[10];
    const float* br_w1     = (const float*)d_in[11];
    const float* br_b1     = (const float*)d_in[12];
    const float* br_w2     = (const float*)d_in[13];
    const float* br_b2     = (const float*)d_in[14];
    float* out = (float*)d_out;

    float* ws  = (float*)d_ws;
    float* h1  = ws;                                     // 12*64*1792 f
    float* dpb = h1 + (size_t)BV * CIN * NPIX;           // 12*1792*32 f
    float* fpb = dpb + (size_t)BV * NPIX * ND;           // 12*1792*128 f
    float* bev = fpb + (size_t)BV * NPIX * BEVC;         // 2*16384*128 f
    float* o2  = bev + (size_t)BQ * BEVH * BEVW * BEVC;  // 2*16384*128 f
    float* Mb  = o2 + (size_t)BQ * BEVH * BEVW * BEVC;   // 21504*128 f
    unsigned short* h2b = (unsigned short*)(Mb + (size_t)NITEM * BEVC); // bf16, NCELL*128
    unsigned short* wf1 = h2b + (size_t)BQ * BEVH * BEVW * BEVC;
    unsigned short* wf2 = wf1 + (size_t)9 * 4 * 8 * 64 * 8;
    unsigned short* wfp = wf2 + (size_t)9 * 4 * 8 * 64 * 8;   // 8192 bf16
    int* cellidx  = (int*)(wfp + 8192);     // NITEM
    int* count    = cellidx + NITEM;        // NCELL
    int* offs     = count + NCELL;          // NCELL+1
    int* cursor   = offs + NCELL + 1;       // NCELL
    int* itemlist = cursor + NCELL;         // NITEM

    // weight prep (fragment-linear bf16)
    k_wprep<<<dim3((9 * 4 * 8 * 64 * 8 + 255) / 256), dim3(256), 0, stream>>>(br_w1, wf1);
    k_wprep<<<dim3((9 * 4 * 8 * 64 * 8 + 255) / 256), dim3(256), 0, stream>>>(br_w2, wf2);
    k_wprep_fp<<<dim3(32), dim3(256), 0, stream>>>(fp_w, wfp);

    // depth-head conv1 + gelu
    k_conv1<<<dim3(BV * NPIX / 256, CIN / COG), dim3(256), 0, stream>>>(feat_maps, dh_w1, dh_b1, h1);

    // depth probs
    k_depth<<<dim3(BV * NPIX / 256), dim3(256), 0, stream>>>(h1, dh_w2, dh_b2, dpb);

    // feature projection (MFMA)
    k_fp<<<dim3(BV * NPIX / 64), dim3(256), 0, stream>>>(feat_maps, wfp, fp_b, fpb);

    // --- scatter via sort+gather (no fp32 atomics) ---
    k_prered<<<dim3(NCOL), dim3(256), 0, stream>>>(fpb, dpb, Km, Tm, trust, depths, Mb, cellidx);
    hipMemsetAsync(count, 0, NCELL * sizeof(int), stream);
    k_hist<<<dim3((NITEM + 255) / 256), dim3(256), 0, stream>>>(cellidx, count);
    k_scan<<<dim3(1), dim3(1024), 0, stream>>>(count, offs, cursor);
    k_fill<<<dim3((NITEM + 255) / 256), dim3(256), 0, stream>>>(cellidx, cursor, itemlist);
    k_gather<<<dim3(NCELL), dim3(BEVC), 0, stream>>>(Mb, offs, itemlist, bev);
    k_fallback<<<dim3(NCOL), dim3(BEVC), 0, stream>>>(fpb, dpb, Km, Tm, trust, depths, cellidx, bev);

    // BEV refinement convs (MFMA): fp32 -> bf16, then bf16 -> fp32
    k_bevconv<0, 1><<<dim3(BEVW / TX2, BEVH / TY2, BQ), dim3(256), 0, stream>>>(bev, wf1, br_b1, h2b);
    k_bevconv<1, 0><<<dim3(BEVW / TX2, BEVH / TY2, BQ), dim3(256), 0, stream>>>(h2b, wf2, br_b2, o2);

    // NHWC -> NCHW
    k_to_nchw<<<dim3(4, BEVH, BQ), dim3(256), 0, stream>>>(o2, out);
}

// Round 9
// 182.257 us; speedup vs baseline: 4.5993x; 1.3793x over previous
//
#include <hip/hip_runtime.h>
#include <hip/hip_bf16.h>
#include <math.h>

#define BQ 2
#define NV 6
#define CIN 64
#define HF 32
#define WF 56
#define ND 32
#define BEVC 128
#define BEVH 128
#define BEVW 128
#define NPIX (HF*WF)     // 1792
#define BV (BQ*NV)       // 12
#define NCOL (BV*WF)     // 672
#define NITEM (NCOL*ND)  // 21504
#define NCELL (BQ*BEVH*BEVW) // 32768
#define EXT 20.0f
#define BN_S 0.99999500003749937f

typedef short bf16x8 __attribute__((ext_vector_type(8)));
typedef float f32x4 __attribute__((ext_vector_type(4)));

__device__ __forceinline__ float gelu(float x) {
    return 0.5f * x * (1.0f + erff(x * 0.70710678118654752f));
}

__device__ __forceinline__ unsigned short f2bf(float x) {
    union { float f; unsigned u; } v; v.f = x;
    unsigned r = v.u + 0x7FFFu + ((v.u >> 16) & 1u);
    return (unsigned short)(r >> 16);
}

// ---------------- conv1 weight prep: w[co][ci][3][3] -> [kpos(9)][kstep(2)][ntile(4)][lane(64)][e(8)] bf16
__global__ void k_wprep_c1(const float* __restrict__ w, unsigned short* __restrict__ wf) {
    int i = blockIdx.x * 256 + threadIdx.x;
    if (i >= 9 * 2 * 4 * 64 * 8) return;
    int e     = i & 7;
    int lane  = (i >> 3) & 63;
    int ntile = (i >> 9) & 3;
    int kstep = (i >> 11) & 1;
    int kpos  = i >> 12;
    int co = ntile * 16 + (lane & 15);
    int ci = kstep * 32 + ((lane >> 4) << 3) + e;
    wf[i] = f2bf(w[((size_t)co * CIN + ci) * 9 + kpos]);
}

// ---------------- Kernel 1: 3x3 conv 64->64 via MFMA bf16, *BN_S, gelu. NCHW in, NHWC out ----
// block 256 (4 waves). Tile 16x * 4y * 64co; wave = one 16-co n-tile. grid (4, 8, BV)
#define C1_HW 18
#define C1_HP (C1_HW*6)   // 108 halo pixels
__global__ void k_conv1(const float* __restrict__ fm, const unsigned short* __restrict__ wfrag,
                        const float* __restrict__ bias, float* __restrict__ h1) {
    __shared__ char als[C1_HP * 128];   // [pix(108)][ci(64) bf16], XOR-swizzled
    int x0 = blockIdx.x * 16;
    int y0 = blockIdx.y * 4;
    int bv = blockIdx.z;
    const float* fmb = fm + (size_t)bv * CIN * NPIX;

    // stage halo: NCHW fp32 -> [pix][ci] bf16
    for (int i = threadIdx.x; i < C1_HP * 8; i += 256) {
        int pix = i >> 3, oct = i & 7;
        int r = pix / C1_HW, c = pix % C1_HW;
        int gy = y0 + r - 1, gx = x0 + c - 1;
        int4 w4 = {0, 0, 0, 0};
        if ((unsigned)gy < (unsigned)HF && (unsigned)gx < (unsigned)WF) {
            const float* p = fmb + (size_t)(oct * 8) * NPIX + gy * WF + gx;
            unsigned short b8[8];
            #pragma unroll
            for (int j = 0; j < 8; j++) b8[j] = f2bf(p[(size_t)j * NPIX]);
            w4.x = b8[0] | ((int)b8[1] << 16);
            w4.y = b8[2] | ((int)b8[3] << 16);
            w4.z = b8[4] | ((int)b8[5] << 16);
            w4.w = b8[6] | ((int)b8[7] << 16);
        }
        *(int4*)(als + pix * 128 + ((oct * 16) ^ ((pix & 7) << 4))) = w4;
    }
    __syncthreads();

    int wave = threadIdx.x >> 6;
    int lane = threadIdx.x & 63;
    int xx   = lane & 15;     // A-row = x position
    int kgrp = lane >> 4;

    const bf16x8* wv = (const bf16x8*)wfrag;
    float bi = bias[wave * 16 + xx];
    f32x4 acc[4];
    #pragma unroll
    for (int m = 0; m < 4; m++) acc[m] = (f32x4){bi, bi, bi, bi};

    for (int kpos = 0; kpos < 9; kpos++) {
        int dy = kpos / 3, dx = kpos % 3;
        #pragma unroll
        for (int kstep = 0; kstep < 2; kstep++) {
            bf16x8 b = wv[((kpos * 2 + kstep) * 4 + wave) * 64 + lane];
            #pragma unroll
            for (int m = 0; m < 4; m++) {
                int pix = (m + dy) * C1_HW + xx + dx;
                bf16x8 a = *(const bf16x8*)(als + pix * 128 +
                                            ((kstep * 64 + kgrp * 16) ^ ((pix & 7) << 4)));
                acc[m] = __builtin_amdgcn_mfma_f32_16x16x32_bf16(a, b, acc[m], 0, 0, 0);
            }
        }
    }

    // D: col=lane&15 -> co-in-tile, row=kgrp*4+r -> x position. Output NHWC [bv][pix][ci]
    #pragma unroll
    for (int m = 0; m < 4; m++) {
        int gy = y0 + m;
        #pragma unroll
        for (int r = 0; r < 4; r++) {
            int gx = x0 + kgrp * 4 + r;
            if (gx < WF)
                h1[((size_t)bv * NPIX + gy * WF + gx) * CIN + wave * 16 + xx] =
                    gelu(acc[m][r] * BN_S);
        }
    }
}

// ---------------- Kernel 2: 1x1 conv 64->32 + softmax over 32. h1 NHWC in, out [p][d] ----------------
__global__ void k_depth(const float* __restrict__ h, const float* __restrict__ w,
                        const float* __restrict__ bias, float* __restrict__ dp) {
    __shared__ float wl[ND * CIN];
    __shared__ float bl[ND];
    for (int i = threadIdx.x; i < ND * CIN; i += 256) wl[i] = w[i];
    if (threadIdx.x < ND) bl[threadIdx.x] = bias[threadIdx.x];
    __syncthreads();
    int g = blockIdx.x * 256 + threadIdx.x;
    if (g >= BV * NPIX) return;
    float hv[CIN];
    const float* hp = h + (size_t)g * CIN;
    #pragma unroll
    for (int c4 = 0; c4 < CIN / 4; c4++) {
        float4 v = ((const float4*)hp)[c4];
        hv[c4 * 4 + 0] = v.x; hv[c4 * 4 + 1] = v.y;
        hv[c4 * 4 + 2] = v.z; hv[c4 * 4 + 3] = v.w;
    }
    float o[ND];
    float mx = -1e30f;
    #pragma unroll
    for (int d = 0; d < ND; d++) {
        float acc = bl[d];
        #pragma unroll
        for (int ci = 0; ci < CIN; ci++) acc += wl[d * CIN + ci] * hv[ci];
        o[d] = acc;
        mx = fmaxf(mx, acc);
    }
    float s = 0.f;
    #pragma unroll
    for (int d = 0; d < ND; d++) { o[d] = expf(o[d] - mx); s += o[d]; }
    float inv = 1.0f / s;
    float* op = dp + (size_t)g * ND;
    #pragma unroll
    for (int d = 0; d < ND; d++) op[d] = o[d] * inv;
}

// ---------------- fp weight prep: w[co][ci] fp32 -> fragment-linear bf16 ----------------
__global__ void k_wprep_fp(const float* __restrict__ w, unsigned short* __restrict__ wf) {
    int i = blockIdx.x * 256 + threadIdx.x;
    if (i >= 2 * 8 * 64 * 8) return;
    int e     = i & 7;
    int lane  = (i >> 3) & 63;
    int ntile = (i >> 9) & 7;
    int kstep = (i >> 12) & 1;
    int co = ntile * 16 + (lane & 15);
    int ci = kstep * 32 + ((lane >> 4) << 3) + e;
    wf[i] = f2bf(w[(size_t)co * CIN + ci]);
}

// ---------------- Kernel 3: 1x1 conv 64->128 via MFMA bf16. out [pix][co] ----------------
__global__ void k_fp(const float* __restrict__ fm, const unsigned short* __restrict__ wfrag,
                     const float* __restrict__ bias, float* __restrict__ fp) {
    __shared__ char als[64 * 128];   // [pix(64)][ci(64) bf16], XOR-swizzled
    int p0 = blockIdx.x * 64;
    int bv = p0 / NPIX, pl0 = p0 % NPIX;
    const float* fmb = fm + (size_t)bv * CIN * NPIX + pl0;

    #pragma unroll
    for (int it = 0; it < 2; it++) {
        int t = threadIdx.x + it * 256;
        int oct = t >> 6, pix = t & 63;
        unsigned short b8[8];
        #pragma unroll
        for (int j = 0; j < 8; j++)
            b8[j] = f2bf(fmb[(size_t)(oct * 8 + j) * NPIX + pix]);
        int4 w4;
        w4.x = b8[0] | ((int)b8[1] << 16);
        w4.y = b8[2] | ((int)b8[3] << 16);
        w4.z = b8[4] | ((int)b8[5] << 16);
        w4.w = b8[6] | ((int)b8[7] << 16);
        *(int4*)(als + pix * 128 + ((oct * 16) ^ ((pix & 7) << 4))) = w4;
    }
    __syncthreads();

    int wave = threadIdx.x >> 6;
    int lane = threadIdx.x & 63;
    int xx   = lane & 15;
    int kgrp = lane >> 4;

    int prow = wave * 16 + xx;
    bf16x8 a0 = *(const bf16x8*)(als + prow * 128 + ((       kgrp * 16) ^ ((prow & 7) << 4)));
    bf16x8 a1 = *(const bf16x8*)(als + prow * 128 + ((64  +  kgrp * 16) ^ ((prow & 7) << 4)));

    const bf16x8* wv = (const bf16x8*)wfrag;

    #pragma unroll
    for (int n = 0; n < 8; n++) {
        float bi = bias[n * 16 + xx];
        f32x4 acc = (f32x4){bi, bi, bi, bi};
        bf16x8 b0 = wv[(0 * 8 + n) * 64 + lane];
        bf16x8 b1 = wv[(1 * 8 + n) * 64 + lane];
        acc = __builtin_amdgcn_mfma_f32_16x16x32_bf16(a0, b0, acc, 0, 0, 0);
        acc = __builtin_amdgcn_mfma_f32_16x16x32_bf16(a1, b1, acc, 0, 0, 0);
        #pragma unroll
        for (int r = 0; r < 4; r++) {
            int pixel = wave * 16 + kgrp * 4 + r;
            fp[(size_t)(p0 + pixel) * BEVC + n * 16 + xx] = gelu(acc[r] * BN_S);
        }
    }
}

// ---------------- geometry helper ----------------
struct Geo {
    float i00,i01,i02,i10,i11,i12,i20,i21,i22;
    float R00,R01,R02,t0,R10,R11,R12,t1;
};
__device__ __forceinline__ Geo load_geo(const float* Km, const float* Tm, int bv) {
    Geo G;
    const float* Kp = Km + bv * 9;
    float a = Kp[0], bb = Kp[1], cc = Kp[2];
    float d = Kp[3], e  = Kp[4], f  = Kp[5];
    float g = Kp[6], hh = Kp[7], ii = Kp[8];
    float A  = e * ii - f * hh;
    float Bm = -(d * ii - f * g);
    float Cm = d * hh - e * g;
    float det = a * A + bb * Bm + cc * Cm;
    float invd = 1.0f / det;
    G.i00 = A * invd;  G.i01 = -(bb * ii - cc * hh) * invd; G.i02 = (bb * f - cc * e) * invd;
    G.i10 = Bm * invd; G.i11 = (a * ii - cc * g) * invd;    G.i12 = -(a * f - cc * d) * invd;
    G.i20 = Cm * invd; G.i21 = -(a * hh - bb * g) * invd;   G.i22 = (a * e - bb * d) * invd;
    const float* Tp = Tm + bv * 16;
    G.R00 = Tp[0]; G.R01 = Tp[1]; G.R02 = Tp[2]; G.t0 = Tp[3];
    G.R10 = Tp[4]; G.R11 = Tp[5]; G.R12 = Tp[6]; G.t1 = Tp[7];
    return G;
}
__device__ __forceinline__ int geo_cell(const Geo& G, int px, int py, float dep) {
    float fx = (float)px, fy = (float)py;
    float r0 = G.i00 * fx + G.i01 * fy + G.i02;
    float r1 = G.i10 * fx + G.i11 * fy + G.i12;
    float r2 = G.i20 * fx + G.i21 * fy + G.i22;
    float xe = G.R00 * (r0 * dep) + G.R01 * (r1 * dep) + G.R02 * (r2 * dep) + G.t0;
    float ye = G.R10 * (r0 * dep) + G.R11 * (r1 * dep) + G.R12 * (r2 * dep) + G.t1;
    int col = (int)((xe + EXT) / (2.0f * EXT) * (float)(BEVW - 1));
    int row = (int)((ye + EXT) / (2.0f * EXT) * (float)(BEVH - 1));
    return (col >= 0 && col < BEVW && row >= 0 && row < BEVH) ? row * BEVW + col : -1;
}

// ---------------- Kernel 4a: per-column py-pre-reduction ----------------
__global__ void k_prered(const float* __restrict__ fp, const float* __restrict__ dp,
                         const float* __restrict__ Km, const float* __restrict__ Tm,
                         const float* __restrict__ trust, const float* __restrict__ depths,
                         float* __restrict__ M, int* __restrict__ cellidx) {
    __shared__ float fpl[HF * BEVC];
    __shared__ float dpl[HF * ND];
    __shared__ int   celll[ND * HF];
    __shared__ int   uni[ND];

    int col = blockIdx.x;
    int bv = col / WF, px = col % WF;
    int b  = bv / NV;
    float tw = trust[bv];

    for (int i = threadIdx.x; i < HF * (BEVC / 4); i += 256) {
        int py = i >> 5, c4 = i & 31;
        float4 v = ((const float4*)(fp + ((size_t)bv * NPIX + py * WF + px) * BEVC))[c4];
        v.x *= tw; v.y *= tw; v.z *= tw; v.w *= tw;
        ((float4*)fpl)[py * 32 + c4] = v;
    }
    for (int i = threadIdx.x; i < HF * (ND / 4); i += 256) {
        int py = i >> 3, d4 = i & 7;
        ((float4*)dpl)[py * 8 + d4] =
            ((const float4*)(dp + ((size_t)bv * NPIX + py * WF + px) * ND))[d4];
    }

    Geo G = load_geo(Km, Tm, bv);
    for (int q = threadIdx.x; q < ND * HF; q += 256) {
        int di = q >> 5, py = q & 31;
        celll[q] = geo_cell(G, px, py, depths[di]);
    }
    __syncthreads();

    if (threadIdx.x < ND) {
        int di = threadIdx.x;
        int c0 = celll[di * HF];
        bool u = true;
        for (int py = 1; py < HF; py++) u &= (celll[di * HF + py] == c0);
        uni[di] = u ? c0 : -2;
    }
    __syncthreads();

    int c = threadIdx.x & 127, dg = threadIdx.x >> 7;
    float acc[16];
    #pragma unroll
    for (int k = 0; k < 16; k++) acc[k] = 0.f;
    for (int py = 0; py < HF; py++) {
        float fv = fpl[py * BEVC + c];
        #pragma unroll
        for (int k = 0; k < 16; k++)
            acc[k] += fv * dpl[py * ND + dg * 16 + k];
    }
    #pragma unroll
    for (int k = 0; k < 16; k++)
        M[((size_t)col * ND + dg * 16 + k) * BEVC + c] = acc[k];

    if (threadIdx.x < ND) {
        int u = uni[threadIdx.x];
        cellidx[col * ND + threadIdx.x] = (u >= 0) ? (b * (BEVH * BEVW) + u) : u;
    }
}

// ---------------- Kernel 4b/c/d: counting sort by cell ----------------
__global__ void k_hist(const int* __restrict__ cellidx, int* __restrict__ count) {
    int i = blockIdx.x * 256 + threadIdx.x;
    if (i >= NITEM) return;
    int c = cellidx[i];
    if (c >= 0) atomicAdd(&count[c], 1);
}

__global__ void k_scan(const int* __restrict__ count, int* __restrict__ offs,
                       int* __restrict__ cursor) {
    __shared__ int part[1024];
    int t = threadIdx.x;
    int base = t * 32;
    int loc[32];
    int s = 0;
    #pragma unroll
    for (int i = 0; i < 32; i++) { loc[i] = s; s += count[base + i]; }
    part[t] = s;
    __syncthreads();
    for (int off = 1; off < 1024; off <<= 1) {
        int v = (t >= off) ? part[t - off] : 0;
        __syncthreads();
        part[t] += v;
        __syncthreads();
    }
    int pre = (t == 0) ? 0 : part[t - 1];
    #pragma unroll
    for (int i = 0; i < 32; i++) {
        offs[base + i] = pre + loc[i];
        cursor[base + i] = pre + loc[i];
    }
    if (t == 1023) offs[NCELL] = pre + s;
}

__global__ void k_fill(const int* __restrict__ cellidx, int* __restrict__ cursor,
                       int* __restrict__ itemlist) {
    int i = blockIdx.x * 256 + threadIdx.x;
    if (i >= NITEM) return;
    int c = cellidx[i];
    if (c >= 0) {
        int p = atomicAdd(&cursor[c], 1);
        itemlist[p] = i;
    }
}

// ---------------- Kernel 4e: gather ----------------
__global__ void k_gather(const float* __restrict__ M, const int* __restrict__ offs,
                         const int* __restrict__ itemlist, float* __restrict__ bev) {
    int cell = blockIdx.x;
    int s = offs[cell], e = offs[cell + 1];
    int c = threadIdx.x;
    float acc = 0.f;
    for (int j = s; j < e; j++) {
        int it = itemlist[j];
        acc += M[(size_t)it * BEVC + c];
    }
    bev[(size_t)cell * BEVC + c] = acc;
}

// ---------------- Kernel 4f: generic fallback (normally no-op) ----------------
__global__ void k_fallback(const float* __restrict__ fp, const float* __restrict__ dp,
                           const float* __restrict__ Km, const float* __restrict__ Tm,
                           const float* __restrict__ trust, const float* __restrict__ depths,
                           const int* __restrict__ cellidx, float* __restrict__ bev) {
    int col = blockIdx.x;
    bool any = false;
    for (int di = 0; di < ND; di++) any |= (cellidx[col * ND + di] == -2);
    if (!any) return;

    int bv = col / WF, px = col % WF;
    int b  = bv / NV;
    float tw = trust[bv];
    Geo G = load_geo(Km, Tm, bv);
    int c = threadIdx.x;
    float* bevb = bev + (size_t)b * BEVH * BEVW * BEVC;
    for (int di = 0; di < ND; di++) {
        if (cellidx[col * ND + di] != -2) continue;
        float dep = depths[di];
        for (int py = 0; py < HF; py++) {
            int cell = geo_cell(G, px, py, dep);
            if (cell >= 0) {
                float v = fp[((size_t)bv * NPIX + py * WF + px) * BEVC + c] * tw *
                          dp[((size_t)bv * NPIX + py * WF + px) * ND + di];
                atomicAdd(&bevb[(size_t)cell * BEVC + c], v);
            }
        }
    }
}

// ---------------- bevconv weight prep ----------------
__global__ void k_wprep(const float* __restrict__ w, unsigned short* __restrict__ wf) {
    int i = blockIdx.x * 256 + threadIdx.x;
    if (i >= 9 * 4 * 8 * 64 * 8) return;
    int e     = i & 7;
    int lane  = (i >> 3) & 63;
    int ntile = (i >> 9) & 7;
    int kstep = (i >> 12) & 3;
    int kpos  = i >> 14;
    int co = ntile * 16 + (lane & 15);
    int ci = kstep * 32 + ((lane >> 4) << 3) + e;
    wf[i] = f2bf(w[((size_t)co * BEVC + ci) * 9 + kpos]);
}

// ---------------- Kernel 5/6: 3x3 conv 128->128 NHWC via MFMA bf16 ----------------
#define TX2 16
#define TY2 4
#define HALO_W 18
#define HALO_H 6
#define HP (HALO_W*HALO_H)   // 108

__device__ __forceinline__ int swz(int pix, int off) {
    return pix * 256 + (off ^ ((pix & 7) << 4));
}

template<int TI_BF, int TO_BF>
__global__ void k_bevconv(const void* __restrict__ in_, const unsigned short* __restrict__ wfrag,
                          const float* __restrict__ bias, void* __restrict__ out_) {
    __shared__ char ldsb[HP * 256];   // [pix(108)][ci(128) bf16], XOR-swizzled
    int x0 = blockIdx.x * TX2;
    int y0 = blockIdx.y * TY2;
    int b  = blockIdx.z;

    for (int t = threadIdx.x; t < HP * 16; t += 256) {
        int pix = t >> 4, oct = t & 15;
        int r = pix / HALO_W, c = pix % HALO_W;
        int gy = y0 + r - 1, gx = x0 + c - 1;
        int4 w4 = {0, 0, 0, 0};
        if ((unsigned)gy < (unsigned)BEVH && (unsigned)gx < (unsigned)BEVW) {
            size_t base = ((size_t)(b * BEVH + gy) * BEVW + gx) * BEVC + oct * 8;
            if (TI_BF) {
                w4 = *(const int4*)((const unsigned short*)in_ + base);
            } else {
                const float* p = (const float*)in_ + base;
                float4 f0 = ((const float4*)p)[0];
                float4 f1 = ((const float4*)p)[1];
                w4.x = f2bf(f0.x) | ((int)f2bf(f0.y) << 16);
                w4.y = f2bf(f0.z) | ((int)f2bf(f0.w) << 16);
                w4.z = f2bf(f1.x) | ((int)f2bf(f1.y) << 16);
                w4.w = f2bf(f1.z) | ((int)f2bf(f1.w) << 16);
            }
        }
        *(int4*)(ldsb + swz(pix, oct * 16)) = w4;
    }
    __syncthreads();

    int wave = threadIdx.x >> 6;
    int lane = threadIdx.x & 63;
    int xx   = lane & 15;
    int kgrp = lane >> 4;

    const bf16x8* wv = (const bf16x8*)wfrag;

    f32x4 acc[TY2][2];
    {
        float b0 = bias[wave * 32 + (lane & 15)];
        float b1 = bias[wave * 32 + 16 + (lane & 15)];
        #pragma unroll
        for (int m = 0; m < TY2; m++) {
            acc[m][0] = (f32x4){b0, b0, b0, b0};
            acc[m][1] = (f32x4){b1, b1, b1, b1};
        }
    }

    for (int kpos = 0; kpos < 9; kpos++) {
        int dy = kpos / 3, dx = kpos % 3;
        #pragma unroll
        for (int kstep = 0; kstep < 4; kstep++) {
            bf16x8 bf0 = wv[((kpos * 4 + kstep) * 8 + wave * 2 + 0) * 64 + lane];
            bf16x8 bf1 = wv[((kpos * 4 + kstep) * 8 + wave * 2 + 1) * 64 + lane];
            #pragma unroll
            for (int m = 0; m < TY2; m++) {
                bf16x8 a = *(const bf16x8*)(ldsb + swz((m + dy) * HALO_W + xx + dx,
                                                       kstep * 64 + kgrp * 16));
                acc[m][0] = __builtin_amdgcn_mfma_f32_16x16x32_bf16(a, bf0, acc[m][0], 0, 0, 0);
                acc[m][1] = __builtin_amdgcn_mfma_f32_16x16x32_bf16(a, bf1, acc[m][1], 0, 0, 0);
            }
        }
    }

    #pragma unroll
    for (int m = 0; m < TY2; m++) {
        int gy = y0 + m;
        #pragma unroll
        for (int n = 0; n < 2; n++) {
            int co = wave * 32 + n * 16 + (lane & 15);
            #pragma unroll
            for (int r = 0; r < 4; r++) {
                int gx = x0 + kgrp * 4 + r;
                float v = gelu(acc[m][n][r] * BN_S);
                size_t oi = ((size_t)(b * BEVH + gy) * BEVW + gx) * BEVC + co;
                if (TO_BF) ((unsigned short*)out_)[oi] = f2bf(v);
                else       ((float*)out_)[oi] = v;
            }
        }
    }
}

// ---------------- NHWC -> NCHW transpose for final output ----------------
__global__ void k_to_nchw(const float* __restrict__ in, float* __restrict__ out) {
    __shared__ float t[64][65];
    int b = blockIdx.z;
    int y = blockIdx.y;
    int xt = (blockIdx.x & 1) * 64;
    int ct = (blockIdx.x >> 1) * 64;
    int lc = threadIdx.x & 63;
    int lr = threadIdx.x >> 6;
    #pragma unroll
    for (int i = 0; i < 16; i++) {
        int xi = lr + i * 4;
        t[xi][lc] = in[(((size_t)b * BEVH + y) * BEVW + xt + xi) * BEVC + ct + lc];
    }
    __syncthreads();
    #pragma unroll
    for (int i = 0; i < 16; i++) {
        int ci = lr + i * 4;
        out[(((size_t)b * BEVC + ct + ci) * BEVH + y) * BEVW + xt + lc] = t[lc][ci];
    }
}

extern "C" void kernel_launch(void* const* d_in, const int* in_sizes, int n_in,
                              void* d_out, int out_size, void* d_ws, size_t ws_size,
                              hipStream_t stream) {
    const float* feat_maps = (const float*)d_in[0];
    const float* Km        = (const float*)d_in[1];
    const float* Tm        = (const float*)d_in[2];
    const float* trust     = (const float*)d_in[3];
    const float* depths    = (const float*)d_in[4];
    const float* dh_w1     = (const float*)d_in[5];
    const float* dh_b1     = (const float*)d_in[6];
    const float* dh_w2     = (const float*)d_in[7];
    const float* dh_b2     = (const float*)d_in[8];
    const float* fp_w      = (const float*)d_in[9];
    const float* fp_b      = (const float*)d_in[10];
    const float* br_w1     = (const float*)d_in[11];
    const float* br_b1     = (const float*)d_in[12];
    const float* br_w2     = (const float*)d_in[13];
    const float* br_b2     = (const float*)d_in[14];
    float* out = (float*)d_out;

    float* ws  = (float*)d_ws;
    float* h1  = ws;                                     // 12*1792*64 f (NHWC)
    float* dpb = h1 + (size_t)BV * CIN * NPIX;           // 12*1792*32 f
    float* fpb = dpb + (size_t)BV * NPIX * ND;           // 12*1792*128 f
    float* bev = fpb + (size_t)BV * NPIX * BEVC;         // 2*16384*128 f
    float* o2  = bev + (size_t)BQ * BEVH * BEVW * BEVC;  // 2*16384*128 f
    float* Mb  = o2 + (size_t)BQ * BEVH * BEVW * BEVC;   // 21504*128 f
    unsigned short* h2b = (unsigned short*)(Mb + (size_t)NITEM * BEVC); // bf16, NCELL*128
    unsigned short* wf1 = h2b + (size_t)BQ * BEVH * BEVW * BEVC;
    unsigned short* wf2 = wf1 + (size_t)9 * 4 * 8 * 64 * 8;
    unsigned short* wfp = wf2 + (size_t)9 * 4 * 8 * 64 * 8;   // 8192 bf16
    unsigned short* wfc1 = wfp + 8192;                        // 36864 bf16
    int* cellidx  = (int*)(wfc1 + 36864);   // NITEM
    int* count    = cellidx + NITEM;        // NCELL
    int* offs     = count + NCELL;          // NCELL+1
    int* cursor   = offs + NCELL + 1;       // NCELL
    int* itemlist = cursor + NCELL;         // NITEM

    // weight prep (fragment-linear bf16)
    k_wprep<<<dim3((9 * 4 * 8 * 64 * 8 + 255) / 256), dim3(256), 0, stream>>>(br_w1, wf1);
    k_wprep<<<dim3((9 * 4 * 8 * 64 * 8 + 255) / 256), dim3(256), 0, stream>>>(br_w2, wf2);
    k_wprep_fp<<<dim3(32), dim3(256), 0, stream>>>(fp_w, wfp);
    k_wprep_c1<<<dim3(144), dim3(256), 0, stream>>>(dh_w1, wfc1);

    // depth-head conv1 + gelu (MFMA, NHWC out)
    k_conv1<<<dim3(4, HF / 4, BV), dim3(256), 0, stream>>>(feat_maps, wfc1, dh_b1, h1);

    // depth probs (NHWC h1)
    k_depth<<<dim3(BV * NPIX / 256), dim3(256), 0, stream>>>(h1, dh_w2, dh_b2, dpb);

    // feature projection (MFMA)
    k_fp<<<dim3(BV * NPIX / 64), dim3(256), 0, stream>>>(feat_maps, wfp, fp_b, fpb);

    // --- scatter via sort+gather (no fp32 atomics) ---
    k_prered<<<dim3(NCOL), dim3(256), 0, stream>>>(fpb, dpb, Km, Tm, trust, depths, Mb, cellidx);
    hipMemsetAsync(count, 0, NCELL * sizeof(int), stream);
    k_hist<<<dim3((NITEM + 255) / 256), dim3(256), 0, stream>>>(cellidx, count);
    k_scan<<<dim3(1), dim3(1024), 0, stream>>>(count, offs, cursor);
    k_fill<<<dim3((NITEM + 255) / 256), dim3(256), 0, stream>>>(cellidx, cursor, itemlist);
    k_gather<<<dim3(NCELL), dim3(BEVC), 0, stream>>>(Mb, offs, itemlist, bev);
    k_fallback<<<dim3(NCOL), dim3(BEVC), 0, stream>>>(fpb, dpb, Km, Tm, trust, depths, cellidx, bev);

    // BEV refinement convs (MFMA): fp32 -> bf16, then bf16 -> fp32
    k_bevconv<0, 1><<<dim3(BEVW / TX2, BEVH / TY2, BQ), dim3(256), 0, stream>>>(bev, wf1, br_b1, h2b);
    k_bevconv<1, 0><<<dim3(BEVW / TX2, BEVH / TY2, BQ), dim3(256), 0, stream>>>(h2b, wf2, br_b2, o2);

    // NHWC -> NCHW
    k_to_nchw<<<dim3(4, BEVH, BQ), dim3(256), 0, stream>>>(o2, out);
}

// Round 10
// 149.918 us; speedup vs baseline: 5.5914x; 1.2157x over previous
//
#include <hip/hip_runtime.h>
#include <hip/hip_bf16.h>
#include <math.h>

#define BQ 2
#define NV 6
#define CIN 64
#define HF 32
#define WF 56
#define ND 32
#define BEVC 128
#define BEVH 128
#define BEVW 128
#define NPIX (HF*WF)     // 1792
#define BV (BQ*NV)       // 12
#define NCOL (BV*WF)     // 672
#define NITEM (NCOL*ND)  // 21504
#define NCELL (BQ*BEVH*BEVW) // 32768
#define EXT 20.0f
#define BN_S 0.99999500003749937f

typedef short bf16x8 __attribute__((ext_vector_type(8)));
typedef float f32x4 __attribute__((ext_vector_type(4)));

__device__ __forceinline__ float gelu(float x) {
    return 0.5f * x * (1.0f + erff(x * 0.70710678118654752f));
}

__device__ __forceinline__ unsigned short f2bf(float x) {
    union { float f; unsigned u; } v; v.f = x;
    unsigned r = v.u + 0x7FFFu + ((v.u >> 16) & 1u);
    return (unsigned short)(r >> 16);
}

// ---------------- combined weight prep + count zeroing ----------------
// seg0: wf1 (147456), seg1: wf2 (147456), seg2: wfp (8192), seg3: wfc1 (36864).
// Also zeroes count[NCELL].
#define WF1_N (9*4*8*64*8)
#define WFP_N (2*8*64*8)
#define WFC1_N (9*2*4*64*8)
__global__ void k_wprep_all(const float* __restrict__ br_w1, const float* __restrict__ br_w2,
                            const float* __restrict__ fp_w, const float* __restrict__ dh_w1,
                            unsigned short* __restrict__ wf1, unsigned short* __restrict__ wf2,
                            unsigned short* __restrict__ wfp, unsigned short* __restrict__ wfc1,
                            int* __restrict__ count) {
    int gi = blockIdx.x * 256 + threadIdx.x;
    if (gi < NCELL) count[gi] = 0;

    int i = gi;
    if (i < 2 * WF1_N) {
        const float* w = (i < WF1_N) ? br_w1 : br_w2;
        unsigned short* wf = (i < WF1_N) ? wf1 : wf2;
        int j = (i < WF1_N) ? i : i - WF1_N;
        int e     = j & 7;
        int lane  = (j >> 3) & 63;
        int ntile = (j >> 9) & 7;
        int kstep = (j >> 12) & 3;
        int kpos  = j >> 14;
        int co = ntile * 16 + (lane & 15);
        int ci = kstep * 32 + ((lane >> 4) << 3) + e;
        wf[j] = f2bf(w[((size_t)co * BEVC + ci) * 9 + kpos]);
        return;
    }
    i -= 2 * WF1_N;
    if (i < WFP_N) {
        int e     = i & 7;
        int lane  = (i >> 3) & 63;
        int ntile = (i >> 9) & 7;
        int kstep = (i >> 12) & 1;
        int co = ntile * 16 + (lane & 15);
        int ci = kstep * 32 + ((lane >> 4) << 3) + e;
        wfp[i] = f2bf(fp_w[(size_t)co * CIN + ci]);
        return;
    }
    i -= WFP_N;
    if (i < WFC1_N) {
        int e     = i & 7;
        int lane  = (i >> 3) & 63;
        int ntile = (i >> 9) & 3;
        int kstep = (i >> 11) & 1;
        int kpos  = i >> 12;
        int co = ntile * 16 + (lane & 15);
        int ci = kstep * 32 + ((lane >> 4) << 3) + e;
        wfc1[i] = f2bf(dh_w1[((size_t)co * CIN + ci) * 9 + kpos]);
    }
}

// ---------------- Kernel 1: fused conv1(MFMA) + depth head + softmax ----------------
// block 256 (4 waves). Tile 16x * 4y * 64co. grid (4, 8, BV). NCHW in, dp out.
#define C1_HW 18
#define C1_HP (C1_HW*6)   // 108 halo pixels
__global__ void k_conv1d(const float* __restrict__ fm, const unsigned short* __restrict__ wfrag,
                         const float* __restrict__ bias, const float* __restrict__ w2,
                         const float* __restrict__ b2, float* __restrict__ dp) {
    __shared__ float hbuf[64 * 65];        // phase A: als halo (char alias); phase B: h tile
    __shared__ float wl2[ND * 65];         // padded depth weights
    __shared__ float bl2[ND];
    char* als = (char*)hbuf;

    int x0 = blockIdx.x * 16;
    int y0 = blockIdx.y * 4;
    int bv = blockIdx.z;
    const float* fmb = fm + (size_t)bv * CIN * NPIX;

    // stage depth weights (padded 65) + bias
    for (int i = threadIdx.x; i < ND * CIN; i += 256) {
        int d = i >> 6, ci = i & 63;
        wl2[d * 65 + ci] = w2[i];
    }
    if (threadIdx.x < ND) bl2[threadIdx.x] = b2[threadIdx.x];

    // stage halo: NCHW fp32 -> [pix][ci] bf16, XOR-swizzled
    for (int i = threadIdx.x; i < C1_HP * 8; i += 256) {
        int pix = i >> 3, oct = i & 7;
        int r = pix / C1_HW, c = pix % C1_HW;
        int gy = y0 + r - 1, gx = x0 + c - 1;
        int4 w4 = {0, 0, 0, 0};
        if ((unsigned)gy < (unsigned)HF && (unsigned)gx < (unsigned)WF) {
            const float* p = fmb + (size_t)(oct * 8) * NPIX + gy * WF + gx;
            unsigned short b8[8];
            #pragma unroll
            for (int j = 0; j < 8; j++) b8[j] = f2bf(p[(size_t)j * NPIX]);
            w4.x = b8[0] | ((int)b8[1] << 16);
            w4.y = b8[2] | ((int)b8[3] << 16);
            w4.z = b8[4] | ((int)b8[5] << 16);
            w4.w = b8[6] | ((int)b8[7] << 16);
        }
        *(int4*)(als + pix * 128 + ((oct * 16) ^ ((pix & 7) << 4))) = w4;
    }
    __syncthreads();

    int wave = threadIdx.x >> 6;
    int lane = threadIdx.x & 63;
    int xx   = lane & 15;
    int kgrp = lane >> 4;

    const bf16x8* wv = (const bf16x8*)wfrag;
    float bi = bias[wave * 16 + xx];
    f32x4 acc[4];
    #pragma unroll
    for (int m = 0; m < 4; m++) acc[m] = (f32x4){bi, bi, bi, bi};

    for (int kpos = 0; kpos < 9; kpos++) {
        int dy = kpos / 3, dx = kpos % 3;
        #pragma unroll
        for (int kstep = 0; kstep < 2; kstep++) {
            bf16x8 b = wv[((kpos * 2 + kstep) * 4 + wave) * 64 + lane];
            #pragma unroll
            for (int m = 0; m < 4; m++) {
                int pix = (m + dy) * C1_HW + xx + dx;
                bf16x8 a = *(const bf16x8*)(als + pix * 128 +
                                            ((kstep * 64 + kgrp * 16) ^ ((pix & 7) << 4)));
                acc[m] = __builtin_amdgcn_mfma_f32_16x16x32_bf16(a, b, acc[m], 0, 0, 0);
            }
        }
    }
    __syncthreads();   // all als reads done; reuse hbuf as h tile

    // write h = gelu(acc*BN_S) to LDS [pixel(64)][co(64)] padded 65
    #pragma unroll
    for (int m = 0; m < 4; m++) {
        #pragma unroll
        for (int r = 0; r < 4; r++) {
            int pixel = m * 16 + kgrp * 4 + r;
            hbuf[pixel * 65 + wave * 16 + xx] = gelu(acc[m][r] * BN_S);
        }
    }
    __syncthreads();

    // depth head: 4 threads per pixel, each 8 of 32 depth logits
    {
        int pixel = threadIdx.x >> 2;
        int part  = threadIdx.x & 3;
        int m = pixel >> 4, xcol = pixel & 15;
        int gy = y0 + m, gx = x0 + xcol;

        float hv[CIN];
        #pragma unroll
        for (int c4 = 0; c4 < CIN / 4; c4++) {
            float4 v = *(const float4*)&hbuf[pixel * 65 + c4 * 4];
            hv[c4 * 4 + 0] = v.x; hv[c4 * 4 + 1] = v.y;
            hv[c4 * 4 + 2] = v.z; hv[c4 * 4 + 3] = v.w;
        }
        float o[8];
        float mx = -1e30f;
        #pragma unroll
        for (int dd = 0; dd < 8; dd++) {
            int d = part * 8 + dd;
            float a = bl2[d];
            #pragma unroll
            for (int ci = 0; ci < CIN; ci++) a += wl2[d * 65 + ci] * hv[ci];
            o[dd] = a;
            mx = fmaxf(mx, a);
        }
        mx = fmaxf(mx, __shfl_xor(mx, 1));
        mx = fmaxf(mx, __shfl_xor(mx, 2));
        float s = 0.f;
        #pragma unroll
        for (int dd = 0; dd < 8; dd++) { o[dd] = expf(o[dd] - mx); s += o[dd]; }
        s += __shfl_xor(s, 1);
        s += __shfl_xor(s, 2);
        float inv = 1.0f / s;
        if (gx < WF) {
            float* op = dp + ((size_t)bv * NPIX + gy * WF + gx) * ND + part * 8;
            float4 v0 = {o[0] * inv, o[1] * inv, o[2] * inv, o[3] * inv};
            float4 v1 = {o[4] * inv, o[5] * inv, o[6] * inv, o[7] * inv};
            ((float4*)op)[0] = v0;
            ((float4*)op)[1] = v1;
        }
    }
}

// ---------------- Kernel 3: 1x1 conv 64->128 via MFMA bf16. out [pix][co] ----------------
__global__ void k_fp(const float* __restrict__ fm, const unsigned short* __restrict__ wfrag,
                     const float* __restrict__ bias, float* __restrict__ fp) {
    __shared__ char als[64 * 128];   // [pix(64)][ci(64) bf16], XOR-swizzled
    int p0 = blockIdx.x * 64;
    int bv = p0 / NPIX, pl0 = p0 % NPIX;
    const float* fmb = fm + (size_t)bv * CIN * NPIX + pl0;

    #pragma unroll
    for (int it = 0; it < 2; it++) {
        int t = threadIdx.x + it * 256;
        int oct = t >> 6, pix = t & 63;
        unsigned short b8[8];
        #pragma unroll
        for (int j = 0; j < 8; j++)
            b8[j] = f2bf(fmb[(size_t)(oct * 8 + j) * NPIX + pix]);
        int4 w4;
        w4.x = b8[0] | ((int)b8[1] << 16);
        w4.y = b8[2] | ((int)b8[3] << 16);
        w4.z = b8[4] | ((int)b8[5] << 16);
        w4.w = b8[6] | ((int)b8[7] << 16);
        *(int4*)(als + pix * 128 + ((oct * 16) ^ ((pix & 7) << 4))) = w4;
    }
    __syncthreads();

    int wave = threadIdx.x >> 6;
    int lane = threadIdx.x & 63;
    int xx   = lane & 15;
    int kgrp = lane >> 4;

    int prow = wave * 16 + xx;
    bf16x8 a0 = *(const bf16x8*)(als + prow * 128 + ((       kgrp * 16) ^ ((prow & 7) << 4)));
    bf16x8 a1 = *(const bf16x8*)(als + prow * 128 + ((64  +  kgrp * 16) ^ ((prow & 7) << 4)));

    const bf16x8* wv = (const bf16x8*)wfrag;

    #pragma unroll
    for (int n = 0; n < 8; n++) {
        float bi = bias[n * 16 + xx];
        f32x4 acc = (f32x4){bi, bi, bi, bi};
        bf16x8 b0 = wv[(0 * 8 + n) * 64 + lane];
        bf16x8 b1 = wv[(1 * 8 + n) * 64 + lane];
        acc = __builtin_amdgcn_mfma_f32_16x16x32_bf16(a0, b0, acc, 0, 0, 0);
        acc = __builtin_amdgcn_mfma_f32_16x16x32_bf16(a1, b1, acc, 0, 0, 0);
        #pragma unroll
        for (int r = 0; r < 4; r++) {
            int pixel = wave * 16 + kgrp * 4 + r;
            fp[(size_t)(p0 + pixel) * BEVC + n * 16 + xx] = gelu(acc[r] * BN_S);
        }
    }
}

// ---------------- geometry helper ----------------
struct Geo {
    float i00,i01,i02,i10,i11,i12,i20,i21,i22;
    float R00,R01,R02,t0,R10,R11,R12,t1;
};
__device__ __forceinline__ Geo load_geo(const float* Km, const float* Tm, int bv) {
    Geo G;
    const float* Kp = Km + bv * 9;
    float a = Kp[0], bb = Kp[1], cc = Kp[2];
    float d = Kp[3], e  = Kp[4], f  = Kp[5];
    float g = Kp[6], hh = Kp[7], ii = Kp[8];
    float A  = e * ii - f * hh;
    float Bm = -(d * ii - f * g);
    float Cm = d * hh - e * g;
    float det = a * A + bb * Bm + cc * Cm;
    float invd = 1.0f / det;
    G.i00 = A * invd;  G.i01 = -(bb * ii - cc * hh) * invd; G.i02 = (bb * f - cc * e) * invd;
    G.i10 = Bm * invd; G.i11 = (a * ii - cc * g) * invd;    G.i12 = -(a * f - cc * d) * invd;
    G.i20 = Cm * invd; G.i21 = -(a * hh - bb * g) * invd;   G.i22 = (a * e - bb * d) * invd;
    const float* Tp = Tm + bv * 16;
    G.R00 = Tp[0]; G.R01 = Tp[1]; G.R02 = Tp[2]; G.t0 = Tp[3];
    G.R10 = Tp[4]; G.R11 = Tp[5]; G.R12 = Tp[6]; G.t1 = Tp[7];
    return G;
}
__device__ __forceinline__ int geo_cell(const Geo& G, int px, int py, float dep) {
    float fx = (float)px, fy = (float)py;
    float r0 = G.i00 * fx + G.i01 * fy + G.i02;
    float r1 = G.i10 * fx + G.i11 * fy + G.i12;
    float r2 = G.i20 * fx + G.i21 * fy + G.i22;
    float xe = G.R00 * (r0 * dep) + G.R01 * (r1 * dep) + G.R02 * (r2 * dep) + G.t0;
    float ye = G.R10 * (r0 * dep) + G.R11 * (r1 * dep) + G.R12 * (r2 * dep) + G.t1;
    int col = (int)((xe + EXT) / (2.0f * EXT) * (float)(BEVW - 1));
    int row = (int)((ye + EXT) / (2.0f * EXT) * (float)(BEVH - 1));
    return (col >= 0 && col < BEVW && row >= 0 && row < BEVH) ? row * BEVW + col : -1;
}

// ---------------- Kernel 4a: per-column py-pre-reduction + histogram ----------------
__global__ void k_prered(const float* __restrict__ fp, const float* __restrict__ dp,
                         const float* __restrict__ Km, const float* __restrict__ Tm,
                         const float* __restrict__ trust, const float* __restrict__ depths,
                         float* __restrict__ M, int* __restrict__ cellidx,
                         int* __restrict__ count) {
    __shared__ float fpl[HF * BEVC];
    __shared__ float dpl[HF * ND];
    __shared__ int   celll[ND * HF];
    __shared__ int   uni[ND];

    int col = blockIdx.x;
    int bv = col / WF, px = col % WF;
    int b  = bv / NV;
    float tw = trust[bv];

    for (int i = threadIdx.x; i < HF * (BEVC / 4); i += 256) {
        int py = i >> 5, c4 = i & 31;
        float4 v = ((const float4*)(fp + ((size_t)bv * NPIX + py * WF + px) * BEVC))[c4];
        v.x *= tw; v.y *= tw; v.z *= tw; v.w *= tw;
        ((float4*)fpl)[py * 32 + c4] = v;
    }
    for (int i = threadIdx.x; i < HF * (ND / 4); i += 256) {
        int py = i >> 3, d4 = i & 7;
        ((float4*)dpl)[py * 8 + d4] =
            ((const float4*)(dp + ((size_t)bv * NPIX + py * WF + px) * ND))[d4];
    }

    Geo G = load_geo(Km, Tm, bv);
    for (int q = threadIdx.x; q < ND * HF; q += 256) {
        int di = q >> 5, py = q & 31;
        celll[q] = geo_cell(G, px, py, depths[di]);
    }
    __syncthreads();

    if (threadIdx.x < ND) {
        int di = threadIdx.x;
        int c0 = celll[di * HF];
        bool u = true;
        for (int py = 1; py < HF; py++) u &= (celll[di * HF + py] == c0);
        uni[di] = u ? c0 : -2;
    }
    __syncthreads();

    int c = threadIdx.x & 127, dg = threadIdx.x >> 7;
    float acc[16];
    #pragma unroll
    for (int k = 0; k < 16; k++) acc[k] = 0.f;
    for (int py = 0; py < HF; py++) {
        float fv = fpl[py * BEVC + c];
        #pragma unroll
        for (int k = 0; k < 16; k++)
            acc[k] += fv * dpl[py * ND + dg * 16 + k];
    }
    #pragma unroll
    for (int k = 0; k < 16; k++)
        M[((size_t)col * ND + dg * 16 + k) * BEVC + c] = acc[k];

    if (threadIdx.x < ND) {
        int u = uni[threadIdx.x];
        int id = (u >= 0) ? (b * (BEVH * BEVW) + u) : u;
        cellidx[col * ND + threadIdx.x] = id;
        if (id >= 0) atomicAdd(&count[id], 1);   // fused histogram
    }
}

// ---------------- Kernel 4c/d: scan + fill ----------------
__global__ void k_scan(const int* __restrict__ count, int* __restrict__ offs,
                       int* __restrict__ cursor) {
    __shared__ int part[1024];
    int t = threadIdx.x;
    int base = t * 32;
    int loc[32];
    int s = 0;
    #pragma unroll
    for (int i = 0; i < 32; i++) { loc[i] = s; s += count[base + i]; }
    part[t] = s;
    __syncthreads();
    for (int off = 1; off < 1024; off <<= 1) {
        int v = (t >= off) ? part[t - off] : 0;
        __syncthreads();
        part[t] += v;
        __syncthreads();
    }
    int pre = (t == 0) ? 0 : part[t - 1];
    #pragma unroll
    for (int i = 0; i < 32; i++) {
        offs[base + i] = pre + loc[i];
        cursor[base + i] = pre + loc[i];
    }
    if (t == 1023) offs[NCELL] = pre + s;
}

__global__ void k_fill(const int* __restrict__ cellidx, int* __restrict__ cursor,
                       int* __restrict__ itemlist) {
    int i = blockIdx.x * 256 + threadIdx.x;
    if (i >= NITEM) return;
    int c = cellidx[i];
    if (c >= 0) {
        int p = atomicAdd(&cursor[c], 1);
        itemlist[p] = i;
    }
}

// ---------------- Kernel 4e: gather ----------------
__global__ void k_gather(const float* __restrict__ M, const int* __restrict__ offs,
                         const int* __restrict__ itemlist, float* __restrict__ bev) {
    int cell = blockIdx.x;
    int s = offs[cell], e = offs[cell + 1];
    int c = threadIdx.x;
    float acc = 0.f;
    for (int j = s; j < e; j++) {
        int it = itemlist[j];
        acc += M[(size_t)it * BEVC + c];
    }
    bev[(size_t)cell * BEVC + c] = acc;
}

// ---------------- Kernel 4f: generic fallback (normally no-op) ----------------
__global__ void k_fallback(const float* __restrict__ fp, const float* __restrict__ dp,
                           const float* __restrict__ Km, const float* __restrict__ Tm,
                           const float* __restrict__ trust, const float* __restrict__ depths,
                           const int* __restrict__ cellidx, float* __restrict__ bev) {
    int col = blockIdx.x;
    bool any = false;
    for (int di = 0; di < ND; di++) any |= (cellidx[col * ND + di] == -2);
    if (!any) return;

    int bv = col / WF, px = col % WF;
    int b  = bv / NV;
    float tw = trust[bv];
    Geo G = load_geo(Km, Tm, bv);
    int c = threadIdx.x;
    float* bevb = bev + (size_t)b * BEVH * BEVW * BEVC;
    for (int di = 0; di < ND; di++) {
        if (cellidx[col * ND + di] != -2) continue;
        float dep = depths[di];
        for (int py = 0; py < HF; py++) {
            int cell = geo_cell(G, px, py, dep);
            if (cell >= 0) {
                float v = fp[((size_t)bv * NPIX + py * WF + px) * BEVC + c] * tw *
                          dp[((size_t)bv * NPIX + py * WF + px) * ND + di];
                atomicAdd(&bevb[(size_t)cell * BEVC + c], v);
            }
        }
    }
}

// ---------------- Kernel 5/6: 3x3 conv 128->128 NHWC via MFMA bf16 ----------------
// TO_MODE: 0 = fp32 NHWC, 1 = bf16 NHWC, 2 = fp32 NCHW (final output, fused transpose)
#define TX2 16
#define TY2 4
#define HALO_W 18
#define HP (HALO_W*6)   // 108

__device__ __forceinline__ int swz(int pix, int off) {
    return pix * 256 + (off ^ ((pix & 7) << 4));
}

template<int TI_BF, int TO_MODE>
__global__ void k_bevconv(const void* __restrict__ in_, const unsigned short* __restrict__ wfrag,
                          const float* __restrict__ bias, void* __restrict__ out_) {
    __shared__ char ldsb[HP * 256];   // [pix(108)][ci(128) bf16], XOR-swizzled
    int x0 = blockIdx.x * TX2;
    int y0 = blockIdx.y * TY2;
    int b  = blockIdx.z;

    for (int t = threadIdx.x; t < HP * 16; t += 256) {
        int pix = t >> 4, oct = t & 15;
        int r = pix / HALO_W, c = pix % HALO_W;
        int gy = y0 + r - 1, gx = x0 + c - 1;
        int4 w4 = {0, 0, 0, 0};
        if ((unsigned)gy < (unsigned)BEVH && (unsigned)gx < (unsigned)BEVW) {
            size_t base = ((size_t)(b * BEVH + gy) * BEVW + gx) * BEVC + oct * 8;
            if (TI_BF) {
                w4 = *(const int4*)((const unsigned short*)in_ + base);
            } else {
                const float* p = (const float*)in_ + base;
                float4 f0 = ((const float4*)p)[0];
                float4 f1 = ((const float4*)p)[1];
                w4.x = f2bf(f0.x) | ((int)f2bf(f0.y) << 16);
                w4.y = f2bf(f0.z) | ((int)f2bf(f0.w) << 16);
                w4.z = f2bf(f1.x) | ((int)f2bf(f1.y) << 16);
                w4.w = f2bf(f1.z) | ((int)f2bf(f1.w) << 16);
            }
        }
        *(int4*)(ldsb + swz(pix, oct * 16)) = w4;
    }
    __syncthreads();

    int wave = threadIdx.x >> 6;
    int lane = threadIdx.x & 63;
    int xx   = lane & 15;
    int kgrp = lane >> 4;

    const bf16x8* wv = (const bf16x8*)wfrag;

    f32x4 acc[TY2][2];
    {
        float b0 = bias[wave * 32 + (lane & 15)];
        float b1 = bias[wave * 32 + 16 + (lane & 15)];
        #pragma unroll
        for (int m = 0; m < TY2; m++) {
            acc[m][0] = (f32x4){b0, b0, b0, b0};
            acc[m][1] = (f32x4){b1, b1, b1, b1};
        }
    }

    for (int kpos = 0; kpos < 9; kpos++) {
        int dy = kpos / 3, dx = kpos % 3;
        #pragma unroll
        for (int kstep = 0; kstep < 4; kstep++) {
            bf16x8 bf0 = wv[((kpos * 4 + kstep) * 8 + wave * 2 + 0) * 64 + lane];
            bf16x8 bf1 = wv[((kpos * 4 + kstep) * 8 + wave * 2 + 1) * 64 + lane];
            #pragma unroll
            for (int m = 0; m < TY2; m++) {
                bf16x8 a = *(const bf16x8*)(ldsb + swz((m + dy) * HALO_W + xx + dx,
                                                       kstep * 64 + kgrp * 16));
                acc[m][0] = __builtin_amdgcn_mfma_f32_16x16x32_bf16(a, bf0, acc[m][0], 0, 0, 0);
                acc[m][1] = __builtin_amdgcn_mfma_f32_16x16x32_bf16(a, bf1, acc[m][1], 0, 0, 0);
            }
        }
    }

    #pragma unroll
    for (int m = 0; m < TY2; m++) {
        int gy = y0 + m;
        #pragma unroll
        for (int n = 0; n < 2; n++) {
            int co = wave * 32 + n * 16 + (lane & 15);
            if (TO_MODE == 2) {
                // fused NHWC->NCHW: 4 contiguous gx per lane -> float4 store
                int gx0 = x0 + kgrp * 4;
                float4 v;
                v.x = gelu(acc[m][n][0] * BN_S);
                v.y = gelu(acc[m][n][1] * BN_S);
                v.z = gelu(acc[m][n][2] * BN_S);
                v.w = gelu(acc[m][n][3] * BN_S);
                *(float4*)((float*)out_ + (((size_t)b * BEVC + co) * BEVH + gy) * BEVW + gx0) = v;
            } else {
                #pragma unroll
                for (int r = 0; r < 4; r++) {
                    int gx = x0 + kgrp * 4 + r;
                    float v = gelu(acc[m][n][r] * BN_S);
                    size_t oi = ((size_t)(b * BEVH + gy) * BEVW + gx) * BEVC + co;
                    if (TO_MODE == 1) ((unsigned short*)out_)[oi] = f2bf(v);
                    else              ((float*)out_)[oi] = v;
                }
            }
        }
    }
}

extern "C" void kernel_launch(void* const* d_in, const int* in_sizes, int n_in,
                              void* d_out, int out_size, void* d_ws, size_t ws_size,
                              hipStream_t stream) {
    const float* feat_maps = (const float*)d_in[0];
    const float* Km        = (const float*)d_in[1];
    const float* Tm        = (const float*)d_in[2];
    const float* trust     = (const float*)d_in[3];
    const float* depths    = (const float*)d_in[4];
    const float* dh_w1     = (const float*)d_in[5];
    const float* dh_b1     = (const float*)d_in[6];
    const float* dh_w2     = (const float*)d_in[7];
    const float* dh_b2     = (const float*)d_in[8];
    const float* fp_w      = (const float*)d_in[9];
    const float* fp_b      = (const float*)d_in[10];
    const float* br_w1     = (const float*)d_in[11];
    const float* br_b1     = (const float*)d_in[12];
    const float* br_w2     = (const float*)d_in[13];
    const float* br_b2     = (const float*)d_in[14];
    float* out = (float*)d_out;

    float* ws  = (float*)d_ws;
    float* dpb = ws;                                     // 12*1792*32 f
    float* fpb = dpb + (size_t)BV * NPIX * ND;           // 12*1792*128 f
    float* bev = fpb + (size_t)BV * NPIX * BEVC;         // 2*16384*128 f
    float* Mb  = bev + (size_t)BQ * BEVH * BEVW * BEVC;  // 21504*128 f
    unsigned short* h2b = (unsigned short*)(Mb + (size_t)NITEM * BEVC); // bf16, NCELL*128
    unsigned short* wf1 = h2b + (size_t)BQ * BEVH * BEVW * BEVC;
    unsigned short* wf2 = wf1 + (size_t)WF1_N;
    unsigned short* wfp = wf2 + (size_t)WF1_N;
    unsigned short* wfc1 = wfp + WFP_N;
    int* cellidx  = (int*)(wfc1 + WFC1_N);  // NITEM
    int* count    = cellidx + NITEM;        // NCELL
    int* offs     = count + NCELL;          // NCELL+1
    int* cursor   = offs + NCELL + 1;       // NCELL
    int* itemlist = cursor + NCELL;         // NITEM

    // combined weight prep + count zeroing
    {
        int total = 2 * WF1_N + WFP_N + WFC1_N;
        k_wprep_all<<<dim3((total + 255) / 256), dim3(256), 0, stream>>>(
            br_w1, br_w2, fp_w, dh_w1, wf1, wf2, wfp, wfc1, count);
    }

    // fused conv1 + depth head + softmax
    k_conv1d<<<dim3(4, HF / 4, BV), dim3(256), 0, stream>>>(
        feat_maps, wfc1, dh_b1, dh_w2, dh_b2, dpb);

    // feature projection (MFMA)
    k_fp<<<dim3(BV * NPIX / 64), dim3(256), 0, stream>>>(feat_maps, wfp, fp_b, fpb);

    // --- scatter via sort+gather (no fp32 atomics) ---
    k_prered<<<dim3(NCOL), dim3(256), 0, stream>>>(fpb, dpb, Km, Tm, trust, depths,
                                                   Mb, cellidx, count);
    k_scan<<<dim3(1), dim3(1024), 0, stream>>>(count, offs, cursor);
    k_fill<<<dim3((NITEM + 255) / 256), dim3(256), 0, stream>>>(cellidx, cursor, itemlist);
    k_gather<<<dim3(NCELL), dim3(BEVC), 0, stream>>>(Mb, offs, itemlist, bev);
    k_fallback<<<dim3(NCOL), dim3(BEVC), 0, stream>>>(fpb, dpb, Km, Tm, trust, depths, cellidx, bev);

    // BEV refinement convs (MFMA): fp32 -> bf16, then bf16 -> fp32 NCHW (fused transpose)
    k_bevconv<0, 1><<<dim3(BEVW / TX2, BEVH / TY2, BQ), dim3(256), 0, stream>>>(bev, wf1, br_b1, h2b);
    k_bevconv<1, 2><<<dim3(BEVW / TX2, BEVH / TY2, BQ), dim3(256), 0, stream>>>(h2b, wf2, br_b2, out);
}